// Round 13
// baseline (466.463 us; speedup 1.0000x reference)
//
#include <hip/hip_runtime.h>
#include <hip/hip_bf16.h>

// EdgeGNN layer: linear1(relu) -> SpMM (CSR counting-sort + gather) -> linear2(relu) -> GRUCell
// E=200000, NNZ=1600000, EF=16, M=128. bf16 MFMA for GEMMs; no f32 atomics.
// R12: fuse msg3 (linear2) into gather. Each 256-thread block gathers a 64-row
//      band of msg2 into LDS (padded [64][136], 2-way banks = free), one barrier,
//      then runs the R8 msg3 GEMM with A-fragments from LDS. Deletes msg2b
//      (102 MB of HBM traffic) + one kernel's launch/stage fixed cost.
//      Gate kept byte-identical to R6/R11 (best measured: 137us, codegen-fragile).

typedef __attribute__((ext_vector_type(4))) float f32x4;
typedef __attribute__((ext_vector_type(8))) short s16x8;

#define MDIM 128
#define EFDIM 16
#define K1PAD 160   // 144 padded to 5*32
#define SCAN_BLK 1024

__device__ __forceinline__ ushort f2bf(float f) {
  union { float f; unsigned u; } v; v.f = f;
  unsigned u = v.u;
  unsigned r = (u + 0x7fffu + ((u >> 16) & 1u)) >> 16;  // RNE
  return (ushort)r;
}
__device__ __forceinline__ float bf2f(ushort h) {
  union { unsigned u; float f; } v; v.u = ((unsigned)h) << 16; return v.f;
}
// native conversion (compiler emits v_cvt_pk_bf16_f32 pairs) - linear1/msg3 path (R8)
__device__ __forceinline__ short f2bfn(float f) {
  __hip_bfloat16 h = __float2bfloat16(f);
  return *reinterpret_cast<short*>(&h);
}
__device__ __forceinline__ s16x8 cvt8n(f32x4 a, f32x4 b) {
  s16x8 o;
  o[0] = f2bfn(a[0]); o[1] = f2bfn(a[1]); o[2] = f2bfn(a[2]); o[3] = f2bfn(a[3]);
  o[4] = f2bfn(b[0]); o[5] = f2bfn(b[1]); o[6] = f2bfn(b[2]); o[7] = f2bfn(b[3]);
  return o;
}
// manual RNE conversion - used by gate (R6 codegen)
__device__ __forceinline__ s16x8 cvt8m(f32x4 a, f32x4 b) {
  s16x8 o;
  o[0] = (short)f2bf(a[0]); o[1] = (short)f2bf(a[1]);
  o[2] = (short)f2bf(a[2]); o[3] = (short)f2bf(a[3]);
  o[4] = (short)f2bf(b[0]); o[5] = (short)f2bf(b[1]);
  o[6] = (short)f2bf(b[2]); o[7] = (short)f2bf(b[3]);
  return o;
}
__device__ __forceinline__ f32x4 mfma16(s16x8 a, s16x8 b, f32x4 c) {
  return __builtin_amdgcn_mfma_f32_16x16x32_bf16(a, b, c, 0, 0, 0);
}
__device__ __forceinline__ float sigmoidf_(float x) { return 1.f / (1.f + __expf(-x)); }
__device__ __forceinline__ float tanhf_(float x) {
  float xc = fminf(fmaxf(x, -15.f), 15.f);
  float t = __expf(2.f * xc);
  return (t - 1.f) / (t + 1.f);
}

// ---------------- prep: bf16 weight conversion ----------------
__global__ __launch_bounds__(256) void prep_kernel(
    const float* __restrict__ W1, const float* __restrict__ W2,
    const float* __restrict__ Wih, const float* __restrict__ Whh,
    ushort* __restrict__ W1b, ushort* __restrict__ W2b,
    ushort* __restrict__ Wihb, ushort* __restrict__ Whhb) {
  int idx = blockIdx.x * 256 + threadIdx.x;
  if (idx < 128 * K1PAD) {
    int n = idx / K1PAD, k = idx % K1PAD;
    W1b[idx] = (k < 144) ? f2bf(W1[n * 144 + k]) : (ushort)0;
    return;
  }
  int i2 = idx - 128 * K1PAD;
  if (i2 < 128 * 128) { W2b[i2] = f2bf(W2[i2]); return; }
  int i3 = i2 - 128 * 128;
  if (i3 < 384 * 128) { Wihb[i3] = f2bf(Wih[i3]); return; }
  int i4 = i3 - 384 * 128;
  if (i4 < 384 * 128) { Whhb[i4] = f2bf(Whh[i4]); return; }
}

// ---------------- K1: msg1 = relu(concat(mo,ef) @ W1^T + b1), bf16 out (R8 version) ----------------
__global__ __launch_bounds__(256) void linear1_kernel(
    const float* __restrict__ mo, const float* __restrict__ ef,
    const ushort* __restrict__ W1b, const float* __restrict__ b1,
    ushort* __restrict__ msg1b) {
  __shared__ ushort w1l[5 * 4096];  // 40KB
  const int tid = threadIdx.x;
  const int wave = tid >> 6, lane = tid & 63;
  const int r = lane & 15, kg = lane >> 4;
  const int row0 = blockIdx.x * 64 + wave * 16;
  const int arow = row0 + r;

  // stage: 2560 granules, 10/thread. gid = step*512 + col*4 + kg
#pragma unroll
  for (int l = 0; l < 10; ++l) {
    const int gid = l * 256 + tid;
    const int stp = gid >> 9, col = (gid >> 2) & 127, kgs = gid & 3;
    uint4 v = *(const uint4*)(W1b + col * K1PAD + stp * 32 + kgs * 8);
    *(uint4*)&w1l[gid * 8] = v;
  }
  __syncthreads();

  f32x4 acc[8] = {};
#pragma unroll
  for (int step = 0; step < 5; ++step) {
    const int k0 = step * 32 + kg * 8;
    s16x8 a;
    if (k0 < 128) {
      f32x4 f1 = *(const f32x4*)(mo + (size_t)arow * MDIM + k0);
      f32x4 f2 = *(const f32x4*)(mo + (size_t)arow * MDIM + k0 + 4);
      a = cvt8n(f1, f2);
    } else if (k0 < 144) {
      f32x4 f1 = *(const f32x4*)(ef + (size_t)arow * EFDIM + (k0 - 128));
      f32x4 f2 = *(const f32x4*)(ef + (size_t)arow * EFDIM + (k0 - 128) + 4);
      a = cvt8n(f1, f2);
    } else {
      a = (s16x8){0, 0, 0, 0, 0, 0, 0, 0};
    }
#pragma unroll
    for (int f = 0; f < 8; ++f) {
      s16x8 b = *(const s16x8*)&w1l[step * 4096 + (f * 16 + r) * 32 + kg * 8];
      acc[f] = mfma16(a, b, acc[f]);
    }
  }
#pragma unroll
  for (int f = 0; f < 8; ++f) {
    const int col = f * 16 + r;
    const float bias = b1[col];
#pragma unroll
    for (int j = 0; j < 4; ++j) {
      const int orow = row0 + kg * 4 + j;
      float v = acc[f][j] + bias;
      v = v > 0.f ? v : 0.f;
      msg1b[(size_t)orow * MDIM + col] = f2bf(v);
    }
  }
}

// ---------------- CSR build: histogram -> scan -> scatter ----------------
__global__ __launch_bounds__(256) void hist_kernel(const int* __restrict__ rows,
                                                   int* __restrict__ cnt, int nnz) {
  int i = blockIdx.x * 256 + threadIdx.x;
  if (i < nnz) atomicAdd(&cnt[rows[i]], 1);
}

__global__ __launch_bounds__(256) void scan1_kernel(const int* __restrict__ cnt,
                                                    int* __restrict__ excl,
                                                    int* __restrict__ bsums, int n) {
  __shared__ int wsum[4];
  const int t = threadIdx.x;
  const int base = blockIdx.x * SCAN_BLK + t * 4;
  int v[4];
#pragma unroll
  for (int j = 0; j < 4; ++j) v[j] = (base + j < n) ? cnt[base + j] : 0;
  const int s = v[0] + v[1] + v[2] + v[3];
  const int lane = t & 63, wave = t >> 6;
  int inc = s;
#pragma unroll
  for (int d = 1; d < 64; d <<= 1) {
    int o = __shfl_up(inc, d, 64);
    if (lane >= d) inc += o;
  }
  if (lane == 63) wsum[wave] = inc;
  __syncthreads();
  int woff = 0;
#pragma unroll
  for (int wv = 0; wv < 4; ++wv) if (wv < wave) woff += wsum[wv];
  int run = woff + inc - s;
#pragma unroll
  for (int j = 0; j < 4; ++j) {
    if (base + j < n) excl[base + j] = run;
    run += v[j];
  }
  if (t == 0) bsums[blockIdx.x] = wsum[0] + wsum[1] + wsum[2] + wsum[3];
}

__global__ __launch_bounds__(256) void scan2_kernel(int* __restrict__ bsums, int nb) {
  __shared__ int ws[4];
  const int t = threadIdx.x;
  const int v = (t < nb) ? bsums[t] : 0;
  const int lane = t & 63, wave = t >> 6;
  int inc = v;
#pragma unroll
  for (int d = 1; d < 64; d <<= 1) {
    int o = __shfl_up(inc, d, 64);
    if (lane >= d) inc += o;
  }
  if (lane == 63) ws[wave] = inc;
  __syncthreads();
  int woff = 0;
#pragma unroll
  for (int wv = 0; wv < 4; ++wv) if (wv < wave) woff += ws[wv];
  if (t < nb) bsums[t] = woff + inc - v;
}

// scatter computes row base on the fly: base = excl[r] + bsums[r>>10]
__global__ __launch_bounds__(256) void scatter_kernel(
    const int* __restrict__ rows, const int* __restrict__ cols,
    const float* __restrict__ vals, const int* __restrict__ excl,
    const int* __restrict__ bsums, int* __restrict__ row_fill,
    int2* __restrict__ csr, int nnz) {
  int i = blockIdx.x * 256 + threadIdx.x;
  if (i >= nnz) return;
  int r = rows[i];
  int base = excl[r] + bsums[r >> 10];
  int idx = base + atomicAdd(&row_fill[r], 1);
  int2 cv;
  cv.x = cols[i];
  cv.y = __float_as_int(vals[i]);
  csr[idx] = cv;
}

// ---------------- fused gather SpMM + msg3 GEMM ----------------
// Block: 256 threads / 4 waves, owns 64 rows. Wave w gathers its own rows
// [w*16, w*16+16) into LDS m2 (padded [64][136] -> 2-way banks, free), with the
// 4-substream x 16-lane per-row pattern. One barrier (covers cross-wave W2
// stage), then the R8 msg3 GEMM with A-fragments from LDS. msg2 never touches HBM.
__global__ __launch_bounds__(256) void gather_msg3_kernel(
    const int* __restrict__ excl, const int* __restrict__ bsums,
    const int2* __restrict__ csr, const ushort* __restrict__ msg1b,
    const ushort* __restrict__ W2b, const float* __restrict__ b2,
    ushort* __restrict__ msg3b, int E, int nnz) {
  __shared__ ushort w2l[4 * 4096];   // 32KB, R8 granule layout
  __shared__ ushort m2[64][136];     // 17KB, +8 pad
  const int tid = threadIdx.x;
  const int wave = tid >> 6, lane = tid & 63;
  const int row0 = blockIdx.x * 64;

  // stage W2: 2048 granules, 8/thread. gid = step*512 + col*4 + kg
#pragma unroll
  for (int l = 0; l < 8; ++l) {
    const int gid = l * 256 + tid;
    const int stp = gid >> 9, col = (gid >> 2) & 127, kgs = gid & 3;
    uint4 v = *(const uint4*)(W2b + col * MDIM + stp * 32 + kgs * 8);
    *(uint4*)&w2l[gid * 8] = v;
  }

  // gather phase: wave handles its own 16 rows sequentially
  const int sub = lane >> 4, c = lane & 15;
  for (int i = 0; i < 16; ++i) {
    const int local = wave * 16 + i;
    const int w = row0 + local;         // E % 64 == 0 -> always < E
    const int start = excl[w] + bsums[w >> 10];
    const int end = (w + 1 < E) ? (excl[w + 1] + bsums[(w + 1) >> 10]) : nnz;

    float acc[8] = {};
    int j = start + sub;
    if (j < end) {
      int2 cv = csr[j];
      while (true) {
        const int jn = j + 4;
        const bool more = jn < end;
        int2 cvn = cv;
        if (more) cvn = csr[jn];
        const float val = __int_as_float(cv.y);
        const s16x8 m = *(const s16x8*)(msg1b + (size_t)cv.x * MDIM + c * 8);
#pragma unroll
        for (int t = 0; t < 8; ++t) acc[t] += bf2f((ushort)m[t]) * val;
        if (!more) break;
        cv = cvn;
        j = jn;
      }
    }
#pragma unroll
    for (int t = 0; t < 8; ++t) {
      acc[t] += __shfl_xor(acc[t], 16, 64);
      acc[t] += __shfl_xor(acc[t], 32, 64);
    }
    if (sub == 0) {
      s16x8 o;
#pragma unroll
      for (int t = 0; t < 8; ++t) o[t] = (short)f2bf(acc[t]);
      *(s16x8*)&m2[local][c * 8] = o;
    }
  }
  __syncthreads();

  // msg3 GEMM (R8 pattern), A-fragments from LDS m2
  const int r = lane & 15, kg = lane >> 4;
  s16x8 a1[4];
#pragma unroll
  for (int step = 0; step < 4; ++step)
    a1[step] = *(const s16x8*)&m2[wave * 16 + r][step * 32 + kg * 8];

  f32x4 acc[8] = {};
#pragma unroll
  for (int step = 0; step < 4; ++step) {
#pragma unroll
    for (int f = 0; f < 8; ++f) {
      s16x8 b = *(const s16x8*)&w2l[step * 4096 + (f * 16 + r) * 32 + kg * 8];
      acc[f] = mfma16(a1[step], b, acc[f]);
    }
  }
#pragma unroll
  for (int f = 0; f < 8; ++f) {
    const int col = f * 16 + r;
    const float bias = b2[col];
#pragma unroll
    for (int j = 0; j < 4; ++j) {
      const int orow = row0 + wave * 16 + kg * 4 + j;
      float v = acc[f][j] + bias;
      v = v > 0.f ? v : 0.f;
      msg3b[(size_t)orow * MDIM + col] = f2bf(v);
    }
  }
}

// ---------------- gate_kernel: GRU gates, 4-way column split (EXACT R6 version) ----------------
// XCD-aware bijective swizzle (m204): the 4 cg-blocks of a row-tile get
// contiguous wgids -> same XCD -> A-panels (msg3, mo) hit that XCD's L2.
__global__ __launch_bounds__(512, 4) void gate_kernel(
    const ushort* __restrict__ msg3b, const float* __restrict__ mo,
    const ushort* __restrict__ Wihb, const ushort* __restrict__ Whhb,
    const float* __restrict__ bih, const float* __restrict__ bhh,
    float* __restrict__ out, int E) {
  __shared__ ushort wl[6 * 4096];  // 48KB: sec l = [l*4096, +4096), 32 rows x 128
  const int tid = threadIdx.x;

  const int nwg = gridDim.x;
  const int orig = blockIdx.x;
  const int q = nwg >> 3, rm = nwg & 7;
  const int xcd = orig & 7, bidx = orig >> 3;
  const int wgid = (xcd < rm ? xcd * (q + 1) : rm * (q + 1) + (xcd - rm) * q) + bidx;
  const int cg = wgid & 3;
  const int row0 = (wgid >> 2) * 128;

  const int wave = tid >> 6, lane = tid & 63;
  const int r = lane & 15, kg = lane >> 4;

  // stage weights: sec l, local row lr (0..31), granule g (0..15)
  const int lr = tid >> 4, g = tid & 15;
#pragma unroll
  for (int l = 0; l < 6; ++l) {
    const ushort* src = (l & 1) ? Whhb : Wihb;
    const int gate = l >> 1;
    uint4 v = *(const uint4*)(src + (size_t)(gate * 128 + cg * 32 + lr) * MDIM + g * 8);
    *(uint4*)&wl[l * 4096 + lr * 128 + ((g * 8) ^ ((lr & 7) << 3))] = v;
  }

  // A-fragments (row-clamped)
  const int arow0 = row0 + wave * 16 + r;
  const int arow = arow0 < E ? arow0 : E - 1;
  s16x8 ai[4], ah[4];
#pragma unroll
  for (int step = 0; step < 4; ++step) {
    const int k0 = step * 32 + kg * 8;
    ai[step] = *(const s16x8*)(msg3b + (size_t)arow * MDIM + k0);
    f32x4 f1 = *(const f32x4*)(mo + (size_t)arow * MDIM + k0);
    f32x4 f2 = *(const f32x4*)(mo + (size_t)arow * MDIM + k0 + 4);
    ah[step] = cvt8m(f1, f2);
  }
  __syncthreads();

  float outv[8];
#pragma unroll
  for (int p = 0; p < 2; ++p) {
    const int slr = p * 16 + r;           // section-local weight row
    f32x4 a_ir = {}, a_hr = {}, a_iz = {}, a_hz = {}, a_in = {}, a_hn = {};
#pragma unroll
    for (int step = 0; step < 4; ++step) {
      const int k0 = step * 32 + kg * 8;
      const int sw = slr * 128 + (k0 ^ ((slr & 7) << 3));
      s16x8 b_ir = *(const s16x8*)&wl[0 * 4096 + sw];
      s16x8 b_hr = *(const s16x8*)&wl[1 * 4096 + sw];
      a_ir = mfma16(ai[step], b_ir, a_ir);
      a_hr = mfma16(ah[step], b_hr, a_hr);
      s16x8 b_iz = *(const s16x8*)&wl[2 * 4096 + sw];
      s16x8 b_hz = *(const s16x8*)&wl[3 * 4096 + sw];
      a_iz = mfma16(ai[step], b_iz, a_iz);
      a_hz = mfma16(ah[step], b_hz, a_hz);
      s16x8 b_in = *(const s16x8*)&wl[4 * 4096 + sw];
      s16x8 b_hn = *(const s16x8*)&wl[5 * 4096 + sw];
      a_in = mfma16(ai[step], b_in, a_in);
      a_hn = mfma16(ah[step], b_hn, a_hn);
    }
    const int c128 = cg * 32 + p * 16 + r;
    const float bi_r = bih[c128], bh_r = bhh[c128];
    const float bi_z = bih[128 + c128], bh_z = bhh[128 + c128];
    const float bi_n = bih[256 + c128], bh_n = bhh[256 + c128];
#pragma unroll
    for (int j = 0; j < 4; ++j) {
      const int orow0 = row0 + wave * 16 + kg * 4 + j;
      const int orow = orow0 < E ? orow0 : E - 1;
      const float rr_ = sigmoidf_((a_ir[j] + bi_r) + (a_hr[j] + bh_r));
      const float zz = sigmoidf_((a_iz[j] + bi_z) + (a_hz[j] + bh_z));
      const float nn = tanhf_((a_in[j] + bi_n) + rr_ * (a_hn[j] + bh_n));
      const float m = mo[(size_t)orow * MDIM + c128];
      outv[p * 4 + j] = (1.f - zz) * nn + zz * m;
    }
  }

  // store burst; nontemporal (out is never re-read; keep L2 for A panels)
#pragma unroll
  for (int p = 0; p < 2; ++p) {
    const int c128 = cg * 32 + p * 16 + r;
#pragma unroll
    for (int j = 0; j < 4; ++j) {
      const int orow = row0 + wave * 16 + kg * 4 + j;
      if (orow < E)
        __builtin_nontemporal_store(outv[p * 4 + j], out + (size_t)orow * MDIM + c128);
    }
  }
}

extern "C" void kernel_launch(void* const* d_in, const int* in_sizes, int n_in,
                              void* d_out, int out_size, void* d_ws, size_t ws_size,
                              hipStream_t stream) {
  const float* ef   = (const float*)d_in[0];
  const float* mo   = (const float*)d_in[1];
  const int*   arow = (const int*)d_in[2];
  const int*   acol = (const int*)d_in[3];
  const float* aval = (const float*)d_in[4];
  const float* W1   = (const float*)d_in[5];
  const float* b1   = (const float*)d_in[6];
  const float* W2   = (const float*)d_in[7];
  const float* b2   = (const float*)d_in[8];
  const float* Wih  = (const float*)d_in[9];
  const float* Whh  = (const float*)d_in[10];
  const float* bih  = (const float*)d_in[11];
  const float* bhh  = (const float*)d_in[12];
  float* out = (float*)d_out;

  const int E   = in_sizes[0] / EFDIM;   // 200000
  const int nnz = in_sizes[2];           // 1600000

  char* w = (char*)d_ws;
  size_t off = 0;
  ushort* msg1b   = (ushort*)(w + off); off += (size_t)E * MDIM * 2;   // 51.2 MB
  ushort* msg3b   = (ushort*)(w + off); off += (size_t)E * MDIM * 2;   // 51.2 MB
  int*    row_cnt = (int*)(w + off);    off += (size_t)E * 4;
  int*    row_fill= (int*)(w + off);    off += (size_t)E * 4;          // adjacent to row_cnt
  int*    excl    = (int*)(w + off);    off += (size_t)E * 4;
  int*    bsums   = (int*)(w + off);    off += 256 * 4;
  int2*   csr     = (int2*)(w + off);   off += (size_t)nnz * 8;        // 12.8 MB
  ushort* W1b     = (ushort*)(w + off); off += 128 * K1PAD * 2;
  ushort* W2b     = (ushort*)(w + off); off += 128 * 128 * 2;
  ushort* Wihb    = (ushort*)(w + off); off += 384 * 128 * 2;
  ushort* Whhb    = (ushort*)(w + off); off += 384 * 128 * 2;
  if (off > ws_size) return;  // needs ~119 MB

  const int prep_elems = 128 * K1PAD + 128 * 128 + 2 * 384 * 128;
  prep_kernel<<<(prep_elems + 255) / 256, 256, 0, stream>>>(W1, W2, Wih, Whh,
                                                            W1b, W2b, Wihb, Whhb);
  // linear1
  linear1_kernel<<<E / 64, 256, 0, stream>>>(mo, ef, W1b, b1, msg1b);

  // CSR build (row_cnt + row_fill zeroed in one memset)
  hipMemsetAsync(row_cnt, 0, (size_t)E * 8, stream);
  hist_kernel<<<(nnz + 255) / 256, 256, 0, stream>>>(arow, row_cnt, nnz);
  const int nscan = (E + SCAN_BLK - 1) / SCAN_BLK;  // 196 blocks
  scan1_kernel<<<nscan, 256, 0, stream>>>(row_cnt, excl, bsums, E);
  scan2_kernel<<<1, 256, 0, stream>>>(bsums, nscan);
  scatter_kernel<<<(nnz + 255) / 256, 256, 0, stream>>>(arow, acol, aval, excl, bsums,
                                                        row_fill, csr, nnz);

  // fused gather SpMM + linear2
  gather_msg3_kernel<<<E / 64, 256, 0, stream>>>(excl, bsums, csr, msg1b, W2b, b2,
                                                 msg3b, E, nnz);

  // GRU gates
  {
    const int nrt = (E + 127) / 128;  // 1563
    gate_kernel<<<nrt * 4, 512, 0, stream>>>(msg3b, mo, Wihb, Whhb, bih, bhh, out, E);
  }
}

// Round 15
// 445.531 us; speedup vs baseline: 1.0470x; 1.0470x over previous
//
#include <hip/hip_runtime.h>
#include <hip/hip_bf16.h>

// EdgeGNN layer: linear1(relu) -> SpMM (CSR counting-sort + gather) -> linear2(relu) -> GRUCell
// E=200000, NNZ=1600000, EF=16, M=128. bf16 MFMA for GEMMs; no f32 atomics.
// R15: R14 retry (compile fix: __builtin_nontemporal_load rejects HIP int2 ->
//      load csr entries as long long). Base = R11 (405.8us best). NT hints on
//      read-once/write-once streams (csr, mo, ef, msg2) to keep per-XCD L2
//      reserved for gather's hot msg1 rows. Gate byte-identical to R6/R11.

typedef __attribute__((ext_vector_type(4))) float f32x4;
typedef __attribute__((ext_vector_type(8))) short s16x8;

#define MDIM 128
#define EFDIM 16
#define K1PAD 160   // 144 padded to 5*32
#define SCAN_BLK 1024

__device__ __forceinline__ ushort f2bf(float f) {
  union { float f; unsigned u; } v; v.f = f;
  unsigned u = v.u;
  unsigned r = (u + 0x7fffu + ((u >> 16) & 1u)) >> 16;  // RNE
  return (ushort)r;
}
__device__ __forceinline__ float bf2f(ushort h) {
  union { unsigned u; float f; } v; v.u = ((unsigned)h) << 16; return v.f;
}
// native conversion (compiler emits v_cvt_pk_bf16_f32 pairs) - linear1/msg3 path (R8)
__device__ __forceinline__ short f2bfn(float f) {
  __hip_bfloat16 h = __float2bfloat16(f);
  return *reinterpret_cast<short*>(&h);
}
__device__ __forceinline__ s16x8 cvt8n(f32x4 a, f32x4 b) {
  s16x8 o;
  o[0] = f2bfn(a[0]); o[1] = f2bfn(a[1]); o[2] = f2bfn(a[2]); o[3] = f2bfn(a[3]);
  o[4] = f2bfn(b[0]); o[5] = f2bfn(b[1]); o[6] = f2bfn(b[2]); o[7] = f2bfn(b[3]);
  return o;
}
// manual RNE conversion - used by gate (R6 codegen)
__device__ __forceinline__ s16x8 cvt8m(f32x4 a, f32x4 b) {
  s16x8 o;
  o[0] = (short)f2bf(a[0]); o[1] = (short)f2bf(a[1]);
  o[2] = (short)f2bf(a[2]); o[3] = (short)f2bf(a[3]);
  o[4] = (short)f2bf(b[0]); o[5] = (short)f2bf(b[1]);
  o[6] = (short)f2bf(b[2]); o[7] = (short)f2bf(b[3]);
  return o;
}
__device__ __forceinline__ f32x4 mfma16(s16x8 a, s16x8 b, f32x4 c) {
  return __builtin_amdgcn_mfma_f32_16x16x32_bf16(a, b, c, 0, 0, 0);
}
__device__ __forceinline__ float sigmoidf_(float x) { return 1.f / (1.f + __expf(-x)); }
__device__ __forceinline__ float tanhf_(float x) {
  float xc = fminf(fmaxf(x, -15.f), 15.f);
  float t = __expf(2.f * xc);
  return (t - 1.f) / (t + 1.f);
}

// ---------------- prep: bf16 weight conversion ----------------
__global__ __launch_bounds__(256) void prep_kernel(
    const float* __restrict__ W1, const float* __restrict__ W2,
    const float* __restrict__ Wih, const float* __restrict__ Whh,
    ushort* __restrict__ W1b, ushort* __restrict__ W2b,
    ushort* __restrict__ Wihb, ushort* __restrict__ Whhb) {
  int idx = blockIdx.x * 256 + threadIdx.x;
  if (idx < 128 * K1PAD) {
    int n = idx / K1PAD, k = idx % K1PAD;
    W1b[idx] = (k < 144) ? f2bf(W1[n * 144 + k]) : (ushort)0;
    return;
  }
  int i2 = idx - 128 * K1PAD;
  if (i2 < 128 * 128) { W2b[i2] = f2bf(W2[i2]); return; }
  int i3 = i2 - 128 * 128;
  if (i3 < 384 * 128) { Wihb[i3] = f2bf(Wih[i3]); return; }
  int i4 = i3 - 384 * 128;
  if (i4 < 384 * 128) { Whhb[i4] = f2bf(Whh[i4]); return; }
}

// ---------------- K1: msg1 = relu(concat(mo,ef) @ W1^T + b1), bf16 out (R8 + NT loads) ----------------
__global__ __launch_bounds__(256) void linear1_kernel(
    const float* __restrict__ mo, const float* __restrict__ ef,
    const ushort* __restrict__ W1b, const float* __restrict__ b1,
    ushort* __restrict__ msg1b) {
  __shared__ ushort w1l[5 * 4096];  // 40KB
  const int tid = threadIdx.x;
  const int wave = tid >> 6, lane = tid & 63;
  const int r = lane & 15, kg = lane >> 4;
  const int row0 = blockIdx.x * 64 + wave * 16;
  const int arow = row0 + r;

  // stage: 2560 granules, 10/thread. gid = step*512 + col*4 + kg
#pragma unroll
  for (int l = 0; l < 10; ++l) {
    const int gid = l * 256 + tid;
    const int stp = gid >> 9, col = (gid >> 2) & 127, kgs = gid & 3;
    uint4 v = *(const uint4*)(W1b + col * K1PAD + stp * 32 + kgs * 8);
    *(uint4*)&w1l[gid * 8] = v;
  }
  __syncthreads();

  f32x4 acc[8] = {};
#pragma unroll
  for (int step = 0; step < 5; ++step) {
    const int k0 = step * 32 + kg * 8;
    s16x8 a;
    if (k0 < 128) {
      f32x4 f1 = __builtin_nontemporal_load((const f32x4*)(mo + (size_t)arow * MDIM + k0));
      f32x4 f2 = __builtin_nontemporal_load((const f32x4*)(mo + (size_t)arow * MDIM + k0 + 4));
      a = cvt8n(f1, f2);
    } else if (k0 < 144) {
      f32x4 f1 = __builtin_nontemporal_load((const f32x4*)(ef + (size_t)arow * EFDIM + (k0 - 128)));
      f32x4 f2 = __builtin_nontemporal_load((const f32x4*)(ef + (size_t)arow * EFDIM + (k0 - 128) + 4));
      a = cvt8n(f1, f2);
    } else {
      a = (s16x8){0, 0, 0, 0, 0, 0, 0, 0};
    }
#pragma unroll
    for (int f = 0; f < 8; ++f) {
      s16x8 b = *(const s16x8*)&w1l[step * 4096 + (f * 16 + r) * 32 + kg * 8];
      acc[f] = mfma16(a, b, acc[f]);
    }
  }
#pragma unroll
  for (int f = 0; f < 8; ++f) {
    const int col = f * 16 + r;
    const float bias = b1[col];
#pragma unroll
    for (int j = 0; j < 4; ++j) {
      const int orow = row0 + kg * 4 + j;
      float v = acc[f][j] + bias;
      v = v > 0.f ? v : 0.f;
      msg1b[(size_t)orow * MDIM + col] = f2bf(v);
    }
  }
}

// ---------------- CSR build: histogram -> scan -> scatter ----------------
__global__ __launch_bounds__(256) void hist_kernel(const int* __restrict__ rows,
                                                   int* __restrict__ cnt, int nnz) {
  int i = blockIdx.x * 256 + threadIdx.x;
  if (i < nnz) atomicAdd(&cnt[rows[i]], 1);
}

__global__ __launch_bounds__(256) void scan1_kernel(const int* __restrict__ cnt,
                                                    int* __restrict__ excl,
                                                    int* __restrict__ bsums, int n) {
  __shared__ int wsum[4];
  const int t = threadIdx.x;
  const int base = blockIdx.x * SCAN_BLK + t * 4;
  int v[4];
#pragma unroll
  for (int j = 0; j < 4; ++j) v[j] = (base + j < n) ? cnt[base + j] : 0;
  const int s = v[0] + v[1] + v[2] + v[3];
  const int lane = t & 63, wave = t >> 6;
  int inc = s;
#pragma unroll
  for (int d = 1; d < 64; d <<= 1) {
    int o = __shfl_up(inc, d, 64);
    if (lane >= d) inc += o;
  }
  if (lane == 63) wsum[wave] = inc;
  __syncthreads();
  int woff = 0;
#pragma unroll
  for (int wv = 0; wv < 4; ++wv) if (wv < wave) woff += wsum[wv];
  int run = woff + inc - s;
#pragma unroll
  for (int j = 0; j < 4; ++j) {
    if (base + j < n) excl[base + j] = run;
    run += v[j];
  }
  if (t == 0) bsums[blockIdx.x] = wsum[0] + wsum[1] + wsum[2] + wsum[3];
}

__global__ __launch_bounds__(256) void scan2_kernel(int* __restrict__ bsums, int nb) {
  __shared__ int ws[4];
  const int t = threadIdx.x;
  const int v = (t < nb) ? bsums[t] : 0;
  const int lane = t & 63, wave = t >> 6;
  int inc = v;
#pragma unroll
  for (int d = 1; d < 64; d <<= 1) {
    int o = __shfl_up(inc, d, 64);
    if (lane >= d) inc += o;
  }
  if (lane == 63) ws[wave] = inc;
  __syncthreads();
  int woff = 0;
#pragma unroll
  for (int wv = 0; wv < 4; ++wv) if (wv < wave) woff += ws[wv];
  if (t < nb) bsums[t] = woff + inc - v;
}

// scatter computes row base on the fly: base = excl[r] + bsums[r>>10]
__global__ __launch_bounds__(256) void scatter_kernel(
    const int* __restrict__ rows, const int* __restrict__ cols,
    const float* __restrict__ vals, const int* __restrict__ excl,
    const int* __restrict__ bsums, int* __restrict__ row_fill,
    int2* __restrict__ csr, int nnz) {
  int i = blockIdx.x * 256 + threadIdx.x;
  if (i >= nnz) return;
  int r = rows[i];
  int base = excl[r] + bsums[r >> 10];
  int idx = base + atomicAdd(&row_fill[r], 1);
  int2 cv;
  cv.x = cols[i];
  cv.y = __float_as_int(vals[i]);
  csr[idx] = cv;
}

// ---------------- gather SpMM: one wave per row, 4 nnz streams x 16 lanes ----------------
// NT hints: csr entries are a read-once stream (loaded as long long: low word =
// col, high word = val bits), msg2b a write-once stream -> keep per-XCD L2
// reserved for the hot msg1 rows.
__global__ __launch_bounds__(256) void gather_kernel(
    const int* __restrict__ excl, const int* __restrict__ bsums,
    const long long* __restrict__ csr,
    const ushort* __restrict__ msg1b, ushort* __restrict__ msg2b,
    int E, int nnz) {
  const int w = (blockIdx.x * 256 + threadIdx.x) >> 6;
  if (w >= E) return;
  const int lane = threadIdx.x & 63;
  const int sub = lane >> 4, c = lane & 15;
  const int start = excl[w] + bsums[w >> 10];
  const int end = (w + 1 < E) ? (excl[w + 1] + bsums[(w + 1) >> 10]) : nnz;

  float acc[8] = {};
  int j = start + sub;
  if (j < end) {
    long long cv = __builtin_nontemporal_load(&csr[j]);
    while (true) {
      const int jn = j + 4;
      const bool more = jn < end;
      long long cvn = cv;
      if (more) cvn = __builtin_nontemporal_load(&csr[jn]);
      const int col = (int)(cv & 0xffffffffll);
      const float val = __int_as_float((int)(cv >> 32));
      const s16x8 m = *(const s16x8*)(msg1b + (size_t)col * MDIM + c * 8);
#pragma unroll
      for (int t = 0; t < 8; ++t) acc[t] += bf2f((ushort)m[t]) * val;
      if (!more) break;
      cv = cvn;
      j = jn;
    }
  }
#pragma unroll
  for (int t = 0; t < 8; ++t) {
    acc[t] += __shfl_xor(acc[t], 16, 64);
    acc[t] += __shfl_xor(acc[t], 32, 64);
  }
  if (sub == 0) {
    s16x8 o;
#pragma unroll
    for (int t = 0; t < 8; ++t) o[t] = (short)f2bf(acc[t]);
    __builtin_nontemporal_store(o, (s16x8*)(msg2b + (size_t)w * MDIM + c * 8));
  }
}

// ---------------- msg3 = relu(msg2 @ W2^T + b2), bf16 out (R8 + NT A-loads) ----------------
__global__ __launch_bounds__(256) void msg3_kernel(
    const ushort* __restrict__ msg2b, const ushort* __restrict__ W2b,
    const float* __restrict__ b2, ushort* __restrict__ msg3b) {
  __shared__ ushort w2l[4 * 4096];  // 32KB
  const int tid = threadIdx.x;
  const int wave = tid >> 6, lane = tid & 63;
  const int r = lane & 15, kg = lane >> 4;
  const int row0 = blockIdx.x * 64 + wave * 16;

  // stage: 2048 granules, 8/thread. gid = step*512 + col*4 + kg
#pragma unroll
  for (int l = 0; l < 8; ++l) {
    const int gid = l * 256 + tid;
    const int stp = gid >> 9, col = (gid >> 2) & 127, kgs = gid & 3;
    uint4 v = *(const uint4*)(W2b + col * MDIM + stp * 32 + kgs * 8);
    *(uint4*)&w2l[gid * 8] = v;
  }

  s16x8 a1[4];
#pragma unroll
  for (int step = 0; step < 4; ++step)
    a1[step] = __builtin_nontemporal_load(
        (const s16x8*)(msg2b + (size_t)(row0 + r) * MDIM + step * 32 + kg * 8));
  __syncthreads();

  f32x4 acc[8] = {};
#pragma unroll
  for (int step = 0; step < 4; ++step) {
#pragma unroll
    for (int f = 0; f < 8; ++f) {
      s16x8 b = *(const s16x8*)&w2l[step * 4096 + (f * 16 + r) * 32 + kg * 8];
      acc[f] = mfma16(a1[step], b, acc[f]);
    }
  }
#pragma unroll
  for (int f = 0; f < 8; ++f) {
    const int col = f * 16 + r;
    const float bias = b2[col];
#pragma unroll
    for (int j = 0; j < 4; ++j) {
      const int orow = row0 + kg * 4 + j;
      float v = acc[f][j] + bias;
      v = v > 0.f ? v : 0.f;
      msg3b[(size_t)orow * MDIM + col] = f2bf(v);
    }
  }
}

// ---------------- gate_kernel: GRU gates, 4-way column split (EXACT R6 version) ----------------
// XCD-aware bijective swizzle (m204): the 4 cg-blocks of a row-tile get
// contiguous wgids -> same XCD -> A-panels (msg3, mo) hit that XCD's L2.
__global__ __launch_bounds__(512, 4) void gate_kernel(
    const ushort* __restrict__ msg3b, const float* __restrict__ mo,
    const ushort* __restrict__ Wihb, const ushort* __restrict__ Whhb,
    const float* __restrict__ bih, const float* __restrict__ bhh,
    float* __restrict__ out, int E) {
  __shared__ ushort wl[6 * 4096];  // 48KB: sec l = [l*4096, +4096), 32 rows x 128
  const int tid = threadIdx.x;

  const int nwg = gridDim.x;
  const int orig = blockIdx.x;
  const int q = nwg >> 3, rm = nwg & 7;
  const int xcd = orig & 7, bidx = orig >> 3;
  const int wgid = (xcd < rm ? xcd * (q + 1) : rm * (q + 1) + (xcd - rm) * q) + bidx;
  const int cg = wgid & 3;
  const int row0 = (wgid >> 2) * 128;

  const int wave = tid >> 6, lane = tid & 63;
  const int r = lane & 15, kg = lane >> 4;

  // stage weights: sec l, local row lr (0..31), granule g (0..15)
  const int lr = tid >> 4, g = tid & 15;
#pragma unroll
  for (int l = 0; l < 6; ++l) {
    const ushort* src = (l & 1) ? Whhb : Wihb;
    const int gate = l >> 1;
    uint4 v = *(const uint4*)(src + (size_t)(gate * 128 + cg * 32 + lr) * MDIM + g * 8);
    *(uint4*)&wl[l * 4096 + lr * 128 + ((g * 8) ^ ((lr & 7) << 3))] = v;
  }

  // A-fragments (row-clamped)
  const int arow0 = row0 + wave * 16 + r;
  const int arow = arow0 < E ? arow0 : E - 1;
  s16x8 ai[4], ah[4];
#pragma unroll
  for (int step = 0; step < 4; ++step) {
    const int k0 = step * 32 + kg * 8;
    ai[step] = *(const s16x8*)(msg3b + (size_t)arow * MDIM + k0);
    f32x4 f1 = *(const f32x4*)(mo + (size_t)arow * MDIM + k0);
    f32x4 f2 = *(const f32x4*)(mo + (size_t)arow * MDIM + k0 + 4);
    ah[step] = cvt8m(f1, f2);
  }
  __syncthreads();

  float outv[8];
#pragma unroll
  for (int p = 0; p < 2; ++p) {
    const int slr = p * 16 + r;           // section-local weight row
    f32x4 a_ir = {}, a_hr = {}, a_iz = {}, a_hz = {}, a_in = {}, a_hn = {};
#pragma unroll
    for (int step = 0; step < 4; ++step) {
      const int k0 = step * 32 + kg * 8;
      const int sw = slr * 128 + (k0 ^ ((slr & 7) << 3));
      s16x8 b_ir = *(const s16x8*)&wl[0 * 4096 + sw];
      s16x8 b_hr = *(const s16x8*)&wl[1 * 4096 + sw];
      a_ir = mfma16(ai[step], b_ir, a_ir);
      a_hr = mfma16(ah[step], b_hr, a_hr);
      s16x8 b_iz = *(const s16x8*)&wl[2 * 4096 + sw];
      s16x8 b_hz = *(const s16x8*)&wl[3 * 4096 + sw];
      a_iz = mfma16(ai[step], b_iz, a_iz);
      a_hz = mfma16(ah[step], b_hz, a_hz);
      s16x8 b_in = *(const s16x8*)&wl[4 * 4096 + sw];
      s16x8 b_hn = *(const s16x8*)&wl[5 * 4096 + sw];
      a_in = mfma16(ai[step], b_in, a_in);
      a_hn = mfma16(ah[step], b_hn, a_hn);
    }
    const int c128 = cg * 32 + p * 16 + r;
    const float bi_r = bih[c128], bh_r = bhh[c128];
    const float bi_z = bih[128 + c128], bh_z = bhh[128 + c128];
    const float bi_n = bih[256 + c128], bh_n = bhh[256 + c128];
#pragma unroll
    for (int j = 0; j < 4; ++j) {
      const int orow0 = row0 + wave * 16 + kg * 4 + j;
      const int orow = orow0 < E ? orow0 : E - 1;
      const float rr_ = sigmoidf_((a_ir[j] + bi_r) + (a_hr[j] + bh_r));
      const float zz = sigmoidf_((a_iz[j] + bi_z) + (a_hz[j] + bh_z));
      const float nn = tanhf_((a_in[j] + bi_n) + rr_ * (a_hn[j] + bh_n));
      const float m = mo[(size_t)orow * MDIM + c128];
      outv[p * 4 + j] = (1.f - zz) * nn + zz * m;
    }
  }

  // store burst; nontemporal (out is never re-read; keep L2 for A panels)
#pragma unroll
  for (int p = 0; p < 2; ++p) {
    const int c128 = cg * 32 + p * 16 + r;
#pragma unroll
    for (int j = 0; j < 4; ++j) {
      const int orow = row0 + wave * 16 + kg * 4 + j;
      if (orow < E)
        __builtin_nontemporal_store(outv[p * 4 + j], out + (size_t)orow * MDIM + c128);
    }
  }
}

extern "C" void kernel_launch(void* const* d_in, const int* in_sizes, int n_in,
                              void* d_out, int out_size, void* d_ws, size_t ws_size,
                              hipStream_t stream) {
  const float* ef   = (const float*)d_in[0];
  const float* mo   = (const float*)d_in[1];
  const int*   arow = (const int*)d_in[2];
  const int*   acol = (const int*)d_in[3];
  const float* aval = (const float*)d_in[4];
  const float* W1   = (const float*)d_in[5];
  const float* b1   = (const float*)d_in[6];
  const float* W2   = (const float*)d_in[7];
  const float* b2   = (const float*)d_in[8];
  const float* Wih  = (const float*)d_in[9];
  const float* Whh  = (const float*)d_in[10];
  const float* bih  = (const float*)d_in[11];
  const float* bhh  = (const float*)d_in[12];
  float* out = (float*)d_out;

  const int E   = in_sizes[0] / EFDIM;   // 200000
  const int nnz = in_sizes[2];           // 1600000

  char* w = (char*)d_ws;
  size_t off = 0;
  ushort* msg1b   = (ushort*)(w + off); off += (size_t)E * MDIM * 2;   // 51.2 MB
  ushort* msg2b   = (ushort*)(w + off); off += (size_t)E * MDIM * 2;   // 51.2 MB
  ushort* msg3b   = (ushort*)(w + off); off += (size_t)E * MDIM * 2;   // 51.2 MB
  int*    row_cnt = (int*)(w + off);    off += (size_t)E * 4;
  int*    row_fill= (int*)(w + off);    off += (size_t)E * 4;          // adjacent to row_cnt
  int*    excl    = (int*)(w + off);    off += (size_t)E * 4;
  int*    bsums   = (int*)(w + off);    off += 256 * 4;
  int2*   csr     = (int2*)(w + off);   off += (size_t)nnz * 8;        // 12.8 MB
  ushort* W1b     = (ushort*)(w + off); off += 128 * K1PAD * 2;
  ushort* W2b     = (ushort*)(w + off); off += 128 * 128 * 2;
  ushort* Wihb    = (ushort*)(w + off); off += 384 * 128 * 2;
  ushort* Whhb    = (ushort*)(w + off); off += 384 * 128 * 2;
  if (off > ws_size) return;  // needs ~170 MB

  const int prep_elems = 128 * K1PAD + 128 * 128 + 2 * 384 * 128;
  prep_kernel<<<(prep_elems + 255) / 256, 256, 0, stream>>>(W1, W2, Wih, Whh,
                                                            W1b, W2b, Wihb, Whhb);
  // linear1
  linear1_kernel<<<E / 64, 256, 0, stream>>>(mo, ef, W1b, b1, msg1b);

  // CSR build (row_cnt + row_fill zeroed in one memset)
  hipMemsetAsync(row_cnt, 0, (size_t)E * 8, stream);
  hist_kernel<<<(nnz + 255) / 256, 256, 0, stream>>>(arow, row_cnt, nnz);
  const int nscan = (E + SCAN_BLK - 1) / SCAN_BLK;  // 196 blocks
  scan1_kernel<<<nscan, 256, 0, stream>>>(row_cnt, excl, bsums, E);
  scan2_kernel<<<1, 256, 0, stream>>>(bsums, nscan);
  scatter_kernel<<<(nnz + 255) / 256, 256, 0, stream>>>(arow, acol, aval, excl, bsums,
                                                        row_fill, csr, nnz);

  // gather SpMM
  {
    const long long total = (long long)E * 64;
    const int grid = (int)((total + 255) / 256);
    gather_kernel<<<grid, 256, 0, stream>>>(excl, bsums, (const long long*)csr,
                                            msg1b, msg2b, E, nnz);
  }

  // linear2 + GRU gates
  msg3_kernel<<<E / 64, 256, 0, stream>>>(msg2b, W2b, b2, msg3b);
  {
    const int nrt = (E + 127) / 128;  // 1563
    gate_kernel<<<nrt * 4, 512, 0, stream>>>(msg3b, mo, Wihb, Whhb, bih, bhh, out, E);
  }
}

// Round 16
// 407.924 us; speedup vs baseline: 1.1435x; 1.0922x over previous
//
#include <hip/hip_runtime.h>
#include <hip/hip_bf16.h>

// EdgeGNN layer: linear1(relu) -> SpMM (CSR counting-sort + gather) -> linear2(relu) -> GRUCell
// E=200000, NNZ=1600000, EF=16, M=128. bf16 MFMA for GEMMs; no f32 atomics.
// R16: full revert of R15's NT hints (regressed +40us: gfx950 NT loads bypass L2
//      that mo/csr/msg2 were using; co-compiled codegen wobble). Base = R11.
//      Gate: 2 tiles per block -- the one untried granularity point between
//      R6 (1 tile, 137us best) and R7 (6 tiles, locality disaster). Amortizes
//      the 48KB weight stage + barrier (~half of block time per MfmaUtil 12%/
//      VALU 44%) over 2x compute while the 4 cg-blocks stay dispatch-synced
//      (drift <= 1 tile). Inner per-tile code byte-identical to R6.

typedef __attribute__((ext_vector_type(4))) float f32x4;
typedef __attribute__((ext_vector_type(8))) short s16x8;

#define MDIM 128
#define EFDIM 16
#define K1PAD 160   // 144 padded to 5*32
#define SCAN_BLK 1024

__device__ __forceinline__ ushort f2bf(float f) {
  union { float f; unsigned u; } v; v.f = f;
  unsigned u = v.u;
  unsigned r = (u + 0x7fffu + ((u >> 16) & 1u)) >> 16;  // RNE
  return (ushort)r;
}
__device__ __forceinline__ float bf2f(ushort h) {
  union { unsigned u; float f; } v; v.u = ((unsigned)h) << 16; return v.f;
}
// native conversion (compiler emits v_cvt_pk_bf16_f32 pairs) - linear1/msg3 path (R8)
__device__ __forceinline__ short f2bfn(float f) {
  __hip_bfloat16 h = __float2bfloat16(f);
  return *reinterpret_cast<short*>(&h);
}
__device__ __forceinline__ s16x8 cvt8n(f32x4 a, f32x4 b) {
  s16x8 o;
  o[0] = f2bfn(a[0]); o[1] = f2bfn(a[1]); o[2] = f2bfn(a[2]); o[3] = f2bfn(a[3]);
  o[4] = f2bfn(b[0]); o[5] = f2bfn(b[1]); o[6] = f2bfn(b[2]); o[7] = f2bfn(b[3]);
  return o;
}
// manual RNE conversion - used by gate (R6 codegen)
__device__ __forceinline__ s16x8 cvt8m(f32x4 a, f32x4 b) {
  s16x8 o;
  o[0] = (short)f2bf(a[0]); o[1] = (short)f2bf(a[1]);
  o[2] = (short)f2bf(a[2]); o[3] = (short)f2bf(a[3]);
  o[4] = (short)f2bf(b[0]); o[5] = (short)f2bf(b[1]);
  o[6] = (short)f2bf(b[2]); o[7] = (short)f2bf(b[3]);
  return o;
}
__device__ __forceinline__ f32x4 mfma16(s16x8 a, s16x8 b, f32x4 c) {
  return __builtin_amdgcn_mfma_f32_16x16x32_bf16(a, b, c, 0, 0, 0);
}
__device__ __forceinline__ float sigmoidf_(float x) { return 1.f / (1.f + __expf(-x)); }
__device__ __forceinline__ float tanhf_(float x) {
  float xc = fminf(fmaxf(x, -15.f), 15.f);
  float t = __expf(2.f * xc);
  return (t - 1.f) / (t + 1.f);
}

// ---------------- prep: bf16 weight conversion ----------------
__global__ __launch_bounds__(256) void prep_kernel(
    const float* __restrict__ W1, const float* __restrict__ W2,
    const float* __restrict__ Wih, const float* __restrict__ Whh,
    ushort* __restrict__ W1b, ushort* __restrict__ W2b,
    ushort* __restrict__ Wihb, ushort* __restrict__ Whhb) {
  int idx = blockIdx.x * 256 + threadIdx.x;
  if (idx < 128 * K1PAD) {
    int n = idx / K1PAD, k = idx % K1PAD;
    W1b[idx] = (k < 144) ? f2bf(W1[n * 144 + k]) : (ushort)0;
    return;
  }
  int i2 = idx - 128 * K1PAD;
  if (i2 < 128 * 128) { W2b[i2] = f2bf(W2[i2]); return; }
  int i3 = i2 - 128 * 128;
  if (i3 < 384 * 128) { Wihb[i3] = f2bf(Wih[i3]); return; }
  int i4 = i3 - 384 * 128;
  if (i4 < 384 * 128) { Whhb[i4] = f2bf(Whh[i4]); return; }
}

// ---------------- K1: msg1 = relu(concat(mo,ef) @ W1^T + b1), bf16 out (R8 version) ----------------
__global__ __launch_bounds__(256) void linear1_kernel(
    const float* __restrict__ mo, const float* __restrict__ ef,
    const ushort* __restrict__ W1b, const float* __restrict__ b1,
    ushort* __restrict__ msg1b) {
  __shared__ ushort w1l[5 * 4096];  // 40KB
  const int tid = threadIdx.x;
  const int wave = tid >> 6, lane = tid & 63;
  const int r = lane & 15, kg = lane >> 4;
  const int row0 = blockIdx.x * 64 + wave * 16;
  const int arow = row0 + r;

  // stage: 2560 granules, 10/thread. gid = step*512 + col*4 + kg
#pragma unroll
  for (int l = 0; l < 10; ++l) {
    const int gid = l * 256 + tid;
    const int stp = gid >> 9, col = (gid >> 2) & 127, kgs = gid & 3;
    uint4 v = *(const uint4*)(W1b + col * K1PAD + stp * 32 + kgs * 8);
    *(uint4*)&w1l[gid * 8] = v;
  }
  __syncthreads();

  f32x4 acc[8] = {};
#pragma unroll
  for (int step = 0; step < 5; ++step) {
    const int k0 = step * 32 + kg * 8;
    s16x8 a;
    if (k0 < 128) {
      f32x4 f1 = *(const f32x4*)(mo + (size_t)arow * MDIM + k0);
      f32x4 f2 = *(const f32x4*)(mo + (size_t)arow * MDIM + k0 + 4);
      a = cvt8n(f1, f2);
    } else if (k0 < 144) {
      f32x4 f1 = *(const f32x4*)(ef + (size_t)arow * EFDIM + (k0 - 128));
      f32x4 f2 = *(const f32x4*)(ef + (size_t)arow * EFDIM + (k0 - 128) + 4);
      a = cvt8n(f1, f2);
    } else {
      a = (s16x8){0, 0, 0, 0, 0, 0, 0, 0};
    }
#pragma unroll
    for (int f = 0; f < 8; ++f) {
      s16x8 b = *(const s16x8*)&w1l[step * 4096 + (f * 16 + r) * 32 + kg * 8];
      acc[f] = mfma16(a, b, acc[f]);
    }
  }
#pragma unroll
  for (int f = 0; f < 8; ++f) {
    const int col = f * 16 + r;
    const float bias = b1[col];
#pragma unroll
    for (int j = 0; j < 4; ++j) {
      const int orow = row0 + kg * 4 + j;
      float v = acc[f][j] + bias;
      v = v > 0.f ? v : 0.f;
      msg1b[(size_t)orow * MDIM + col] = f2bf(v);
    }
  }
}

// ---------------- CSR build: histogram -> scan -> scatter ----------------
__global__ __launch_bounds__(256) void hist_kernel(const int* __restrict__ rows,
                                                   int* __restrict__ cnt, int nnz) {
  int i = blockIdx.x * 256 + threadIdx.x;
  if (i < nnz) atomicAdd(&cnt[rows[i]], 1);
}

__global__ __launch_bounds__(256) void scan1_kernel(const int* __restrict__ cnt,
                                                    int* __restrict__ excl,
                                                    int* __restrict__ bsums, int n) {
  __shared__ int wsum[4];
  const int t = threadIdx.x;
  const int base = blockIdx.x * SCAN_BLK + t * 4;
  int v[4];
#pragma unroll
  for (int j = 0; j < 4; ++j) v[j] = (base + j < n) ? cnt[base + j] : 0;
  const int s = v[0] + v[1] + v[2] + v[3];
  const int lane = t & 63, wave = t >> 6;
  int inc = s;
#pragma unroll
  for (int d = 1; d < 64; d <<= 1) {
    int o = __shfl_up(inc, d, 64);
    if (lane >= d) inc += o;
  }
  if (lane == 63) wsum[wave] = inc;
  __syncthreads();
  int woff = 0;
#pragma unroll
  for (int wv = 0; wv < 4; ++wv) if (wv < wave) woff += wsum[wv];
  int run = woff + inc - s;
#pragma unroll
  for (int j = 0; j < 4; ++j) {
    if (base + j < n) excl[base + j] = run;
    run += v[j];
  }
  if (t == 0) bsums[blockIdx.x] = wsum[0] + wsum[1] + wsum[2] + wsum[3];
}

__global__ __launch_bounds__(256) void scan2_kernel(int* __restrict__ bsums, int nb) {
  __shared__ int ws[4];
  const int t = threadIdx.x;
  const int v = (t < nb) ? bsums[t] : 0;
  const int lane = t & 63, wave = t >> 6;
  int inc = v;
#pragma unroll
  for (int d = 1; d < 64; d <<= 1) {
    int o = __shfl_up(inc, d, 64);
    if (lane >= d) inc += o;
  }
  if (lane == 63) ws[wave] = inc;
  __syncthreads();
  int woff = 0;
#pragma unroll
  for (int wv = 0; wv < 4; ++wv) if (wv < wave) woff += ws[wv];
  if (t < nb) bsums[t] = woff + inc - v;
}

// scatter computes row base on the fly: base = excl[r] + bsums[r>>10]
__global__ __launch_bounds__(256) void scatter_kernel(
    const int* __restrict__ rows, const int* __restrict__ cols,
    const float* __restrict__ vals, const int* __restrict__ excl,
    const int* __restrict__ bsums, int* __restrict__ row_fill,
    int2* __restrict__ csr, int nnz) {
  int i = blockIdx.x * 256 + threadIdx.x;
  if (i >= nnz) return;
  int r = rows[i];
  int base = excl[r] + bsums[r >> 10];
  int idx = base + atomicAdd(&row_fill[r], 1);
  int2 cv;
  cv.x = cols[i];
  cv.y = __float_as_int(vals[i]);
  csr[idx] = cv;
}

// ---------------- gather SpMM: one wave per row, 4 nnz streams x 16 lanes (R11 version) ----------------
__global__ __launch_bounds__(256) void gather_kernel(
    const int* __restrict__ excl, const int* __restrict__ bsums,
    const int2* __restrict__ csr,
    const ushort* __restrict__ msg1b, ushort* __restrict__ msg2b,
    int E, int nnz) {
  const int w = (blockIdx.x * 256 + threadIdx.x) >> 6;
  if (w >= E) return;
  const int lane = threadIdx.x & 63;
  const int sub = lane >> 4, c = lane & 15;
  const int start = excl[w] + bsums[w >> 10];
  const int end = (w + 1 < E) ? (excl[w + 1] + bsums[(w + 1) >> 10]) : nnz;

  float acc[8] = {};
  int j = start + sub;
  if (j < end) {
    int2 cv = csr[j];
    while (true) {
      const int jn = j + 4;
      const bool more = jn < end;
      int2 cvn = cv;
      if (more) cvn = csr[jn];
      const float val = __int_as_float(cv.y);
      const s16x8 m = *(const s16x8*)(msg1b + (size_t)cv.x * MDIM + c * 8);
#pragma unroll
      for (int t = 0; t < 8; ++t) acc[t] += bf2f((ushort)m[t]) * val;
      if (!more) break;
      cv = cvn;
      j = jn;
    }
  }
#pragma unroll
  for (int t = 0; t < 8; ++t) {
    acc[t] += __shfl_xor(acc[t], 16, 64);
    acc[t] += __shfl_xor(acc[t], 32, 64);
  }
  if (sub == 0) {
    s16x8 o;
#pragma unroll
    for (int t = 0; t < 8; ++t) o[t] = (short)f2bf(acc[t]);
    *(s16x8*)(msg2b + (size_t)w * MDIM + c * 8) = o;
  }
}

// ---------------- msg3 = relu(msg2 @ W2^T + b2), bf16 out (R8 version) ----------------
__global__ __launch_bounds__(256) void msg3_kernel(
    const ushort* __restrict__ msg2b, const ushort* __restrict__ W2b,
    const float* __restrict__ b2, ushort* __restrict__ msg3b) {
  __shared__ ushort w2l[4 * 4096];  // 32KB
  const int tid = threadIdx.x;
  const int wave = tid >> 6, lane = tid & 63;
  const int r = lane & 15, kg = lane >> 4;
  const int row0 = blockIdx.x * 64 + wave * 16;

  // stage: 2048 granules, 8/thread. gid = step*512 + col*4 + kg
#pragma unroll
  for (int l = 0; l < 8; ++l) {
    const int gid = l * 256 + tid;
    const int stp = gid >> 9, col = (gid >> 2) & 127, kgs = gid & 3;
    uint4 v = *(const uint4*)(W2b + col * MDIM + stp * 32 + kgs * 8);
    *(uint4*)&w2l[gid * 8] = v;
  }

  s16x8 a1[4];
#pragma unroll
  for (int step = 0; step < 4; ++step)
    a1[step] = *(const s16x8*)(msg2b + (size_t)(row0 + r) * MDIM + step * 32 + kg * 8);
  __syncthreads();

  f32x4 acc[8] = {};
#pragma unroll
  for (int step = 0; step < 4; ++step) {
#pragma unroll
    for (int f = 0; f < 8; ++f) {
      s16x8 b = *(const s16x8*)&w2l[step * 4096 + (f * 16 + r) * 32 + kg * 8];
      acc[f] = mfma16(a1[step], b, acc[f]);
    }
  }
#pragma unroll
  for (int f = 0; f < 8; ++f) {
    const int col = f * 16 + r;
    const float bias = b2[col];
#pragma unroll
    for (int j = 0; j < 4; ++j) {
      const int orow = row0 + kg * 4 + j;
      float v = acc[f][j] + bias;
      v = v > 0.f ? v : 0.f;
      msg3b[(size_t)orow * MDIM + col] = f2bf(v);
    }
  }
}

// ---------------- gate_kernel: GRU gates, 4-way column split, 2 tiles/block ----------------
// R6 inner code verbatim; outer loop runs 2 consecutive 128-row tiles per block,
// amortizing the 48KB weight stage + barrier. The 4 cg-blocks of a tile-pair get
// contiguous wgids (XCD-bijective swizzle) -> same XCD, dispatch-synced.
__global__ __launch_bounds__(512, 4) void gate_kernel(
    const ushort* __restrict__ msg3b, const float* __restrict__ mo,
    const ushort* __restrict__ Wihb, const ushort* __restrict__ Whhb,
    const float* __restrict__ bih, const float* __restrict__ bhh,
    float* __restrict__ out, int E, int ntiles) {
  __shared__ ushort wl[6 * 4096];  // 48KB: sec l = [l*4096, +4096), 32 rows x 128
  const int tid = threadIdx.x;

  const int nwg = gridDim.x;
  const int orig = blockIdx.x;
  const int q = nwg >> 3, rm = nwg & 7;
  const int xcd = orig & 7, bidx = orig >> 3;
  const int wgid = (xcd < rm ? xcd * (q + 1) : rm * (q + 1) + (xcd - rm) * q) + bidx;
  const int cg = wgid & 3;
  const int tile0 = (wgid >> 2) * 2;

  const int wave = tid >> 6, lane = tid & 63;
  const int r = lane & 15, kg = lane >> 4;

  // stage weights once: sec l, local row lr (0..31), granule g (0..15)
  const int lr = tid >> 4, g = tid & 15;
#pragma unroll
  for (int l = 0; l < 6; ++l) {
    const ushort* src = (l & 1) ? Whhb : Wihb;
    const int gate = l >> 1;
    uint4 v = *(const uint4*)(src + (size_t)(gate * 128 + cg * 32 + lr) * MDIM + g * 8);
    *(uint4*)&wl[l * 4096 + lr * 128 + ((g * 8) ^ ((lr & 7) << 3))] = v;
  }
  __syncthreads();

  for (int tt = 0; tt < 2; ++tt) {
    const int tile = tile0 + tt;
    if (tile >= ntiles) break;
    const int row0 = tile * 128;

    // A-fragments (row-clamped)
    const int arow0 = row0 + wave * 16 + r;
    const int arow = arow0 < E ? arow0 : E - 1;
    s16x8 ai[4], ah[4];
#pragma unroll
    for (int step = 0; step < 4; ++step) {
      const int k0 = step * 32 + kg * 8;
      ai[step] = *(const s16x8*)(msg3b + (size_t)arow * MDIM + k0);
      f32x4 f1 = *(const f32x4*)(mo + (size_t)arow * MDIM + k0);
      f32x4 f2 = *(const f32x4*)(mo + (size_t)arow * MDIM + k0 + 4);
      ah[step] = cvt8m(f1, f2);
    }

    float outv[8];
#pragma unroll
    for (int p = 0; p < 2; ++p) {
      const int slr = p * 16 + r;           // section-local weight row
      f32x4 a_ir = {}, a_hr = {}, a_iz = {}, a_hz = {}, a_in = {}, a_hn = {};
#pragma unroll
      for (int step = 0; step < 4; ++step) {
        const int k0 = step * 32 + kg * 8;
        const int sw = slr * 128 + (k0 ^ ((slr & 7) << 3));
        s16x8 b_ir = *(const s16x8*)&wl[0 * 4096 + sw];
        s16x8 b_hr = *(const s16x8*)&wl[1 * 4096 + sw];
        a_ir = mfma16(ai[step], b_ir, a_ir);
        a_hr = mfma16(ah[step], b_hr, a_hr);
        s16x8 b_iz = *(const s16x8*)&wl[2 * 4096 + sw];
        s16x8 b_hz = *(const s16x8*)&wl[3 * 4096 + sw];
        a_iz = mfma16(ai[step], b_iz, a_iz);
        a_hz = mfma16(ah[step], b_hz, a_hz);
        s16x8 b_in = *(const s16x8*)&wl[4 * 4096 + sw];
        s16x8 b_hn = *(const s16x8*)&wl[5 * 4096 + sw];
        a_in = mfma16(ai[step], b_in, a_in);
        a_hn = mfma16(ah[step], b_hn, a_hn);
      }
      const int c128 = cg * 32 + p * 16 + r;
      const float bi_r = bih[c128], bh_r = bhh[c128];
      const float bi_z = bih[128 + c128], bh_z = bhh[128 + c128];
      const float bi_n = bih[256 + c128], bh_n = bhh[256 + c128];
#pragma unroll
      for (int j = 0; j < 4; ++j) {
        const int orow0j = row0 + wave * 16 + kg * 4 + j;
        const int orow = orow0j < E ? orow0j : E - 1;
        const float rr_ = sigmoidf_((a_ir[j] + bi_r) + (a_hr[j] + bh_r));
        const float zz = sigmoidf_((a_iz[j] + bi_z) + (a_hz[j] + bh_z));
        const float nn = tanhf_((a_in[j] + bi_n) + rr_ * (a_hn[j] + bh_n));
        const float m = mo[(size_t)orow * MDIM + c128];
        outv[p * 4 + j] = (1.f - zz) * nn + zz * m;
      }
    }

    // store burst; nontemporal (out is never re-read; keep L2 for A panels)
#pragma unroll
    for (int p = 0; p < 2; ++p) {
      const int c128 = cg * 32 + p * 16 + r;
#pragma unroll
      for (int j = 0; j < 4; ++j) {
        const int orow = row0 + wave * 16 + kg * 4 + j;
        if (orow < E)
          __builtin_nontemporal_store(outv[p * 4 + j], out + (size_t)orow * MDIM + c128);
      }
    }
  }
}

extern "C" void kernel_launch(void* const* d_in, const int* in_sizes, int n_in,
                              void* d_out, int out_size, void* d_ws, size_t ws_size,
                              hipStream_t stream) {
  const float* ef   = (const float*)d_in[0];
  const float* mo   = (const float*)d_in[1];
  const int*   arow = (const int*)d_in[2];
  const int*   acol = (const int*)d_in[3];
  const float* aval = (const float*)d_in[4];
  const float* W1   = (const float*)d_in[5];
  const float* b1   = (const float*)d_in[6];
  const float* W2   = (const float*)d_in[7];
  const float* b2   = (const float*)d_in[8];
  const float* Wih  = (const float*)d_in[9];
  const float* Whh  = (const float*)d_in[10];
  const float* bih  = (const float*)d_in[11];
  const float* bhh  = (const float*)d_in[12];
  float* out = (float*)d_out;

  const int E   = in_sizes[0] / EFDIM;   // 200000
  const int nnz = in_sizes[2];           // 1600000

  char* w = (char*)d_ws;
  size_t off = 0;
  ushort* msg1b   = (ushort*)(w + off); off += (size_t)E * MDIM * 2;   // 51.2 MB
  ushort* msg2b   = (ushort*)(w + off); off += (size_t)E * MDIM * 2;   // 51.2 MB
  ushort* msg3b   = (ushort*)(w + off); off += (size_t)E * MDIM * 2;   // 51.2 MB
  int*    row_cnt = (int*)(w + off);    off += (size_t)E * 4;
  int*    row_fill= (int*)(w + off);    off += (size_t)E * 4;          // adjacent to row_cnt
  int*    excl    = (int*)(w + off);    off += (size_t)E * 4;
  int*    bsums   = (int*)(w + off);    off += 256 * 4;
  int2*   csr     = (int2*)(w + off);   off += (size_t)nnz * 8;        // 12.8 MB
  ushort* W1b     = (ushort*)(w + off); off += 128 * K1PAD * 2;
  ushort* W2b     = (ushort*)(w + off); off += 128 * 128 * 2;
  ushort* Wihb    = (ushort*)(w + off); off += 384 * 128 * 2;
  ushort* Whhb    = (ushort*)(w + off); off += 384 * 128 * 2;
  if (off > ws_size) return;  // needs ~170 MB

  const int prep_elems = 128 * K1PAD + 128 * 128 + 2 * 384 * 128;
  prep_kernel<<<(prep_elems + 255) / 256, 256, 0, stream>>>(W1, W2, Wih, Whh,
                                                            W1b, W2b, Wihb, Whhb);
  // linear1
  linear1_kernel<<<E / 64, 256, 0, stream>>>(mo, ef, W1b, b1, msg1b);

  // CSR build (row_cnt + row_fill zeroed in one memset)
  hipMemsetAsync(row_cnt, 0, (size_t)E * 8, stream);
  hist_kernel<<<(nnz + 255) / 256, 256, 0, stream>>>(arow, row_cnt, nnz);
  const int nscan = (E + SCAN_BLK - 1) / SCAN_BLK;  // 196 blocks
  scan1_kernel<<<nscan, 256, 0, stream>>>(row_cnt, excl, bsums, E);
  scan2_kernel<<<1, 256, 0, stream>>>(bsums, nscan);
  scatter_kernel<<<(nnz + 255) / 256, 256, 0, stream>>>(arow, acol, aval, excl, bsums,
                                                        row_fill, csr, nnz);

  // gather SpMM
  {
    const long long total = (long long)E * 64;
    const int grid = (int)((total + 255) / 256);
    gather_kernel<<<grid, 256, 0, stream>>>(excl, bsums, csr, msg1b, msg2b, E, nnz);
  }

  // linear2 + GRU gates (2 tiles per block)
  msg3_kernel<<<E / 64, 256, 0, stream>>>(msg2b, W2b, b2, msg3b);
  {
    const int ntiles = (E + 127) / 128;          // 1563
    const int npairs = (ntiles + 1) / 2;         // 782
    gate_kernel<<<npairs * 4, 512, 0, stream>>>(msg3b, mo, Wihb, Whhb, bih, bhh,
                                                out, E, ntiles);
  }
}

// Round 17
// 407.869 us; speedup vs baseline: 1.1437x; 1.0001x over previous
//
#include <hip/hip_runtime.h>
#include <hip/hip_bf16.h>

// EdgeGNN layer: linear1(relu) -> SpMM (CSR counting-sort + gather) -> linear2(relu) -> GRUCell
// E=200000, NNZ=1600000, EF=16, M=128. bf16 MFMA for GEMMs; no f32 atomics.
// R17: single-variable experiment on R11 base (405.8us best): gate's A-fragment
//      conversion manual-RNE (5 ops/elem, ~160 VALU/thread) -> native
//      v_cvt_pk_bf16_f32 (~16 ops). R8/R9 confounded this with layout changes;
//      never isolated. Gate VALUBusy=44% is the largest remaining utilization.
//      All other kernels byte-identical to R11.

typedef __attribute__((ext_vector_type(4))) float f32x4;
typedef __attribute__((ext_vector_type(8))) short s16x8;

#define MDIM 128
#define EFDIM 16
#define K1PAD 160   // 144 padded to 5*32
#define SCAN_BLK 1024

__device__ __forceinline__ ushort f2bf(float f) {
  union { float f; unsigned u; } v; v.f = f;
  unsigned u = v.u;
  unsigned r = (u + 0x7fffu + ((u >> 16) & 1u)) >> 16;  // RNE
  return (ushort)r;
}
__device__ __forceinline__ float bf2f(ushort h) {
  union { unsigned u; float f; } v; v.u = ((unsigned)h) << 16; return v.f;
}
// native conversion (compiler emits v_cvt_pk_bf16_f32 pairs)
__device__ __forceinline__ short f2bfn(float f) {
  __hip_bfloat16 h = __float2bfloat16(f);
  return *reinterpret_cast<short*>(&h);
}
__device__ __forceinline__ s16x8 cvt8n(f32x4 a, f32x4 b) {
  s16x8 o;
  o[0] = f2bfn(a[0]); o[1] = f2bfn(a[1]); o[2] = f2bfn(a[2]); o[3] = f2bfn(a[3]);
  o[4] = f2bfn(b[0]); o[5] = f2bfn(b[1]); o[6] = f2bfn(b[2]); o[7] = f2bfn(b[3]);
  return o;
}
__device__ __forceinline__ f32x4 mfma16(s16x8 a, s16x8 b, f32x4 c) {
  return __builtin_amdgcn_mfma_f32_16x16x32_bf16(a, b, c, 0, 0, 0);
}
__device__ __forceinline__ float sigmoidf_(float x) { return 1.f / (1.f + __expf(-x)); }
__device__ __forceinline__ float tanhf_(float x) {
  float xc = fminf(fmaxf(x, -15.f), 15.f);
  float t = __expf(2.f * xc);
  return (t - 1.f) / (t + 1.f);
}

// ---------------- prep: bf16 weight conversion ----------------
__global__ __launch_bounds__(256) void prep_kernel(
    const float* __restrict__ W1, const float* __restrict__ W2,
    const float* __restrict__ Wih, const float* __restrict__ Whh,
    ushort* __restrict__ W1b, ushort* __restrict__ W2b,
    ushort* __restrict__ Wihb, ushort* __restrict__ Whhb) {
  int idx = blockIdx.x * 256 + threadIdx.x;
  if (idx < 128 * K1PAD) {
    int n = idx / K1PAD, k = idx % K1PAD;
    W1b[idx] = (k < 144) ? f2bf(W1[n * 144 + k]) : (ushort)0;
    return;
  }
  int i2 = idx - 128 * K1PAD;
  if (i2 < 128 * 128) { W2b[i2] = f2bf(W2[i2]); return; }
  int i3 = i2 - 128 * 128;
  if (i3 < 384 * 128) { Wihb[i3] = f2bf(Wih[i3]); return; }
  int i4 = i3 - 384 * 128;
  if (i4 < 384 * 128) { Whhb[i4] = f2bf(Whh[i4]); return; }
}

// ---------------- K1: msg1 = relu(concat(mo,ef) @ W1^T + b1), bf16 out (R8 version) ----------------
__global__ __launch_bounds__(256) void linear1_kernel(
    const float* __restrict__ mo, const float* __restrict__ ef,
    const ushort* __restrict__ W1b, const float* __restrict__ b1,
    ushort* __restrict__ msg1b) {
  __shared__ ushort w1l[5 * 4096];  // 40KB
  const int tid = threadIdx.x;
  const int wave = tid >> 6, lane = tid & 63;
  const int r = lane & 15, kg = lane >> 4;
  const int row0 = blockIdx.x * 64 + wave * 16;
  const int arow = row0 + r;

  // stage: 2560 granules, 10/thread. gid = step*512 + col*4 + kg
#pragma unroll
  for (int l = 0; l < 10; ++l) {
    const int gid = l * 256 + tid;
    const int stp = gid >> 9, col = (gid >> 2) & 127, kgs = gid & 3;
    uint4 v = *(const uint4*)(W1b + col * K1PAD + stp * 32 + kgs * 8);
    *(uint4*)&w1l[gid * 8] = v;
  }
  __syncthreads();

  f32x4 acc[8] = {};
#pragma unroll
  for (int step = 0; step < 5; ++step) {
    const int k0 = step * 32 + kg * 8;
    s16x8 a;
    if (k0 < 128) {
      f32x4 f1 = *(const f32x4*)(mo + (size_t)arow * MDIM + k0);
      f32x4 f2 = *(const f32x4*)(mo + (size_t)arow * MDIM + k0 + 4);
      a = cvt8n(f1, f2);
    } else if (k0 < 144) {
      f32x4 f1 = *(const f32x4*)(ef + (size_t)arow * EFDIM + (k0 - 128));
      f32x4 f2 = *(const f32x4*)(ef + (size_t)arow * EFDIM + (k0 - 128) + 4);
      a = cvt8n(f1, f2);
    } else {
      a = (s16x8){0, 0, 0, 0, 0, 0, 0, 0};
    }
#pragma unroll
    for (int f = 0; f < 8; ++f) {
      s16x8 b = *(const s16x8*)&w1l[step * 4096 + (f * 16 + r) * 32 + kg * 8];
      acc[f] = mfma16(a, b, acc[f]);
    }
  }
#pragma unroll
  for (int f = 0; f < 8; ++f) {
    const int col = f * 16 + r;
    const float bias = b1[col];
#pragma unroll
    for (int j = 0; j < 4; ++j) {
      const int orow = row0 + kg * 4 + j;
      float v = acc[f][j] + bias;
      v = v > 0.f ? v : 0.f;
      msg1b[(size_t)orow * MDIM + col] = f2bf(v);
    }
  }
}

// ---------------- CSR build: histogram -> scan -> scatter ----------------
__global__ __launch_bounds__(256) void hist_kernel(const int* __restrict__ rows,
                                                   int* __restrict__ cnt, int nnz) {
  int i = blockIdx.x * 256 + threadIdx.x;
  if (i < nnz) atomicAdd(&cnt[rows[i]], 1);
}

__global__ __launch_bounds__(256) void scan1_kernel(const int* __restrict__ cnt,
                                                    int* __restrict__ excl,
                                                    int* __restrict__ bsums, int n) {
  __shared__ int wsum[4];
  const int t = threadIdx.x;
  const int base = blockIdx.x * SCAN_BLK + t * 4;
  int v[4];
#pragma unroll
  for (int j = 0; j < 4; ++j) v[j] = (base + j < n) ? cnt[base + j] : 0;
  const int s = v[0] + v[1] + v[2] + v[3];
  const int lane = t & 63, wave = t >> 6;
  int inc = s;
#pragma unroll
  for (int d = 1; d < 64; d <<= 1) {
    int o = __shfl_up(inc, d, 64);
    if (lane >= d) inc += o;
  }
  if (lane == 63) wsum[wave] = inc;
  __syncthreads();
  int woff = 0;
#pragma unroll
  for (int wv = 0; wv < 4; ++wv) if (wv < wave) woff += wsum[wv];
  int run = woff + inc - s;
#pragma unroll
  for (int j = 0; j < 4; ++j) {
    if (base + j < n) excl[base + j] = run;
    run += v[j];
  }
  if (t == 0) bsums[blockIdx.x] = wsum[0] + wsum[1] + wsum[2] + wsum[3];
}

__global__ __launch_bounds__(256) void scan2_kernel(int* __restrict__ bsums, int nb) {
  __shared__ int ws[4];
  const int t = threadIdx.x;
  const int v = (t < nb) ? bsums[t] : 0;
  const int lane = t & 63, wave = t >> 6;
  int inc = v;
#pragma unroll
  for (int d = 1; d < 64; d <<= 1) {
    int o = __shfl_up(inc, d, 64);
    if (lane >= d) inc += o;
  }
  if (lane == 63) ws[wave] = inc;
  __syncthreads();
  int woff = 0;
#pragma unroll
  for (int wv = 0; wv < 4; ++wv) if (wv < wave) woff += ws[wv];
  if (t < nb) bsums[t] = woff + inc - v;
}

// scatter computes row base on the fly: base = excl[r] + bsums[r>>10]
__global__ __launch_bounds__(256) void scatter_kernel(
    const int* __restrict__ rows, const int* __restrict__ cols,
    const float* __restrict__ vals, const int* __restrict__ excl,
    const int* __restrict__ bsums, int* __restrict__ row_fill,
    int2* __restrict__ csr, int nnz) {
  int i = blockIdx.x * 256 + threadIdx.x;
  if (i >= nnz) return;
  int r = rows[i];
  int base = excl[r] + bsums[r >> 10];
  int idx = base + atomicAdd(&row_fill[r], 1);
  int2 cv;
  cv.x = cols[i];
  cv.y = __float_as_int(vals[i]);
  csr[idx] = cv;
}

// ---------------- gather SpMM: one wave per row, 4 nnz streams x 16 lanes (R11 version) ----------------
__global__ __launch_bounds__(256) void gather_kernel(
    const int* __restrict__ excl, const int* __restrict__ bsums,
    const int2* __restrict__ csr,
    const ushort* __restrict__ msg1b, ushort* __restrict__ msg2b,
    int E, int nnz) {
  const int w = (blockIdx.x * 256 + threadIdx.x) >> 6;
  if (w >= E) return;
  const int lane = threadIdx.x & 63;
  const int sub = lane >> 4, c = lane & 15;
  const int start = excl[w] + bsums[w >> 10];
  const int end = (w + 1 < E) ? (excl[w + 1] + bsums[(w + 1) >> 10]) : nnz;

  float acc[8] = {};
  int j = start + sub;
  if (j < end) {
    int2 cv = csr[j];
    while (true) {
      const int jn = j + 4;
      const bool more = jn < end;
      int2 cvn = cv;
      if (more) cvn = csr[jn];
      const float val = __int_as_float(cv.y);
      const s16x8 m = *(const s16x8*)(msg1b + (size_t)cv.x * MDIM + c * 8);
#pragma unroll
      for (int t = 0; t < 8; ++t) acc[t] += bf2f((ushort)m[t]) * val;
      if (!more) break;
      cv = cvn;
      j = jn;
    }
  }
#pragma unroll
  for (int t = 0; t < 8; ++t) {
    acc[t] += __shfl_xor(acc[t], 16, 64);
    acc[t] += __shfl_xor(acc[t], 32, 64);
  }
  if (sub == 0) {
    s16x8 o;
#pragma unroll
    for (int t = 0; t < 8; ++t) o[t] = (short)f2bf(acc[t]);
    *(s16x8*)(msg2b + (size_t)w * MDIM + c * 8) = o;
  }
}

// ---------------- msg3 = relu(msg2 @ W2^T + b2), bf16 out (R8 version) ----------------
__global__ __launch_bounds__(256) void msg3_kernel(
    const ushort* __restrict__ msg2b, const ushort* __restrict__ W2b,
    const float* __restrict__ b2, ushort* __restrict__ msg3b) {
  __shared__ ushort w2l[4 * 4096];  // 32KB
  const int tid = threadIdx.x;
  const int wave = tid >> 6, lane = tid & 63;
  const int r = lane & 15, kg = lane >> 4;
  const int row0 = blockIdx.x * 64 + wave * 16;

  // stage: 2048 granules, 8/thread. gid = step*512 + col*4 + kg
#pragma unroll
  for (int l = 0; l < 8; ++l) {
    const int gid = l * 256 + tid;
    const int stp = gid >> 9, col = (gid >> 2) & 127, kgs = gid & 3;
    uint4 v = *(const uint4*)(W2b + col * MDIM + stp * 32 + kgs * 8);
    *(uint4*)&w2l[gid * 8] = v;
  }

  s16x8 a1[4];
#pragma unroll
  for (int step = 0; step < 4; ++step)
    a1[step] = *(const s16x8*)(msg2b + (size_t)(row0 + r) * MDIM + step * 32 + kg * 8);
  __syncthreads();

  f32x4 acc[8] = {};
#pragma unroll
  for (int step = 0; step < 4; ++step) {
#pragma unroll
    for (int f = 0; f < 8; ++f) {
      s16x8 b = *(const s16x8*)&w2l[step * 4096 + (f * 16 + r) * 32 + kg * 8];
      acc[f] = mfma16(a1[step], b, acc[f]);
    }
  }
#pragma unroll
  for (int f = 0; f < 8; ++f) {
    const int col = f * 16 + r;
    const float bias = b2[col];
#pragma unroll
    for (int j = 0; j < 4; ++j) {
      const int orow = row0 + kg * 4 + j;
      float v = acc[f][j] + bias;
      v = v > 0.f ? v : 0.f;
      msg3b[(size_t)orow * MDIM + col] = f2bf(v);
    }
  }
}

// ---------------- gate_kernel: GRU gates, 4-way column split (R6 structure, native cvt) ----------------
// XCD-aware bijective swizzle (m204): the 4 cg-blocks of a row-tile get
// contiguous wgids -> same XCD -> A-panels (msg3, mo) hit that XCD's L2.
// R17 change (ONLY): cvt8m -> cvt8n for the mo A-fragment conversion.
__global__ __launch_bounds__(512, 4) void gate_kernel(
    const ushort* __restrict__ msg3b, const float* __restrict__ mo,
    const ushort* __restrict__ Wihb, const ushort* __restrict__ Whhb,
    const float* __restrict__ bih, const float* __restrict__ bhh,
    float* __restrict__ out, int E) {
  __shared__ ushort wl[6 * 4096];  // 48KB: sec l = [l*4096, +4096), 32 rows x 128
  const int tid = threadIdx.x;

  const int nwg = gridDim.x;
  const int orig = blockIdx.x;
  const int q = nwg >> 3, rm = nwg & 7;
  const int xcd = orig & 7, bidx = orig >> 3;
  const int wgid = (xcd < rm ? xcd * (q + 1) : rm * (q + 1) + (xcd - rm) * q) + bidx;
  const int cg = wgid & 3;
  const int row0 = (wgid >> 2) * 128;

  const int wave = tid >> 6, lane = tid & 63;
  const int r = lane & 15, kg = lane >> 4;

  // stage weights: sec l, local row lr (0..31), granule g (0..15)
  const int lr = tid >> 4, g = tid & 15;
#pragma unroll
  for (int l = 0; l < 6; ++l) {
    const ushort* src = (l & 1) ? Whhb : Wihb;
    const int gate = l >> 1;
    uint4 v = *(const uint4*)(src + (size_t)(gate * 128 + cg * 32 + lr) * MDIM + g * 8);
    *(uint4*)&wl[l * 4096 + lr * 128 + ((g * 8) ^ ((lr & 7) << 3))] = v;
  }

  // A-fragments (row-clamped)
  const int arow0 = row0 + wave * 16 + r;
  const int arow = arow0 < E ? arow0 : E - 1;
  s16x8 ai[4], ah[4];
#pragma unroll
  for (int step = 0; step < 4; ++step) {
    const int k0 = step * 32 + kg * 8;
    ai[step] = *(const s16x8*)(msg3b + (size_t)arow * MDIM + k0);
    f32x4 f1 = *(const f32x4*)(mo + (size_t)arow * MDIM + k0);
    f32x4 f2 = *(const f32x4*)(mo + (size_t)arow * MDIM + k0 + 4);
    ah[step] = cvt8n(f1, f2);
  }
  __syncthreads();

  float outv[8];
#pragma unroll
  for (int p = 0; p < 2; ++p) {
    const int slr = p * 16 + r;           // section-local weight row
    f32x4 a_ir = {}, a_hr = {}, a_iz = {}, a_hz = {}, a_in = {}, a_hn = {};
#pragma unroll
    for (int step = 0; step < 4; ++step) {
      const int k0 = step * 32 + kg * 8;
      const int sw = slr * 128 + (k0 ^ ((slr & 7) << 3));
      s16x8 b_ir = *(const s16x8*)&wl[0 * 4096 + sw];
      s16x8 b_hr = *(const s16x8*)&wl[1 * 4096 + sw];
      a_ir = mfma16(ai[step], b_ir, a_ir);
      a_hr = mfma16(ah[step], b_hr, a_hr);
      s16x8 b_iz = *(const s16x8*)&wl[2 * 4096 + sw];
      s16x8 b_hz = *(const s16x8*)&wl[3 * 4096 + sw];
      a_iz = mfma16(ai[step], b_iz, a_iz);
      a_hz = mfma16(ah[step], b_hz, a_hz);
      s16x8 b_in = *(const s16x8*)&wl[4 * 4096 + sw];
      s16x8 b_hn = *(const s16x8*)&wl[5 * 4096 + sw];
      a_in = mfma16(ai[step], b_in, a_in);
      a_hn = mfma16(ah[step], b_hn, a_hn);
    }
    const int c128 = cg * 32 + p * 16 + r;
    const float bi_r = bih[c128], bh_r = bhh[c128];
    const float bi_z = bih[128 + c128], bh_z = bhh[128 + c128];
    const float bi_n = bih[256 + c128], bh_n = bhh[256 + c128];
#pragma unroll
    for (int j = 0; j < 4; ++j) {
      const int orow0 = row0 + wave * 16 + kg * 4 + j;
      const int orow = orow0 < E ? orow0 : E - 1;
      const float rr_ = sigmoidf_((a_ir[j] + bi_r) + (a_hr[j] + bh_r));
      const float zz = sigmoidf_((a_iz[j] + bi_z) + (a_hz[j] + bh_z));
      const float nn = tanhf_((a_in[j] + bi_n) + rr_ * (a_hn[j] + bh_n));
      const float m = mo[(size_t)orow * MDIM + c128];
      outv[p * 4 + j] = (1.f - zz) * nn + zz * m;
    }
  }

  // store burst; nontemporal (out is never re-read; keep L2 for A panels)
#pragma unroll
  for (int p = 0; p < 2; ++p) {
    const int c128 = cg * 32 + p * 16 + r;
#pragma unroll
    for (int j = 0; j < 4; ++j) {
      const int orow = row0 + wave * 16 + kg * 4 + j;
      if (orow < E)
        __builtin_nontemporal_store(outv[p * 4 + j], out + (size_t)orow * MDIM + c128);
    }
  }
}

extern "C" void kernel_launch(void* const* d_in, const int* in_sizes, int n_in,
                              void* d_out, int out_size, void* d_ws, size_t ws_size,
                              hipStream_t stream) {
  const float* ef   = (const float*)d_in[0];
  const float* mo   = (const float*)d_in[1];
  const int*   arow = (const int*)d_in[2];
  const int*   acol = (const int*)d_in[3];
  const float* aval = (const float*)d_in[4];
  const float* W1   = (const float*)d_in[5];
  const float* b1   = (const float*)d_in[6];
  const float* W2   = (const float*)d_in[7];
  const float* b2   = (const float*)d_in[8];
  const float* Wih  = (const float*)d_in[9];
  const float* Whh  = (const float*)d_in[10];
  const float* bih  = (const float*)d_in[11];
  const float* bhh  = (const float*)d_in[12];
  float* out = (float*)d_out;

  const int E   = in_sizes[0] / EFDIM;   // 200000
  const int nnz = in_sizes[2];           // 1600000

  char* w = (char*)d_ws;
  size_t off = 0;
  ushort* msg1b   = (ushort*)(w + off); off += (size_t)E * MDIM * 2;   // 51.2 MB
  ushort* msg2b   = (ushort*)(w + off); off += (size_t)E * MDIM * 2;   // 51.2 MB
  ushort* msg3b   = (ushort*)(w + off); off += (size_t)E * MDIM * 2;   // 51.2 MB
  int*    row_cnt = (int*)(w + off);    off += (size_t)E * 4;
  int*    row_fill= (int*)(w + off);    off += (size_t)E * 4;          // adjacent to row_cnt
  int*    excl    = (int*)(w + off);    off += (size_t)E * 4;
  int*    bsums   = (int*)(w + off);    off += 256 * 4;
  int2*   csr     = (int2*)(w + off);   off += (size_t)nnz * 8;        // 12.8 MB
  ushort* W1b     = (ushort*)(w + off); off += 128 * K1PAD * 2;
  ushort* W2b     = (ushort*)(w + off); off += 128 * 128 * 2;
  ushort* Wihb    = (ushort*)(w + off); off += 384 * 128 * 2;
  ushort* Whhb    = (ushort*)(w + off); off += 384 * 128 * 2;
  if (off > ws_size) return;  // needs ~170 MB

  const int prep_elems = 128 * K1PAD + 128 * 128 + 2 * 384 * 128;
  prep_kernel<<<(prep_elems + 255) / 256, 256, 0, stream>>>(W1, W2, Wih, Whh,
                                                            W1b, W2b, Wihb, Whhb);
  // linear1
  linear1_kernel<<<E / 64, 256, 0, stream>>>(mo, ef, W1b, b1, msg1b);

  // CSR build (row_cnt + row_fill zeroed in one memset)
  hipMemsetAsync(row_cnt, 0, (size_t)E * 8, stream);
  hist_kernel<<<(nnz + 255) / 256, 256, 0, stream>>>(arow, row_cnt, nnz);
  const int nscan = (E + SCAN_BLK - 1) / SCAN_BLK;  // 196 blocks
  scan1_kernel<<<nscan, 256, 0, stream>>>(row_cnt, excl, bsums, E);
  scan2_kernel<<<1, 256, 0, stream>>>(bsums, nscan);
  scatter_kernel<<<(nnz + 255) / 256, 256, 0, stream>>>(arow, acol, aval, excl, bsums,
                                                        row_fill, csr, nnz);

  // gather SpMM
  {
    const long long total = (long long)E * 64;
    const int grid = (int)((total + 255) / 256);
    gather_kernel<<<grid, 256, 0, stream>>>(excl, bsums, csr, msg1b, msg2b, E, nnz);
  }

  // linear2 + GRU gates
  msg3_kernel<<<E / 64, 256, 0, stream>>>(msg2b, W2b, b2, msg3b);
  {
    const int nrt = (E + 127) / 128;  // 1563
    gate_kernel<<<nrt * 4, 512, 0, stream>>>(msg3b, mo, Wihb, Whhb, bih, bhh, out, E);
  }
}

// Round 18
// 399.373 us; speedup vs baseline: 1.1680x; 1.0213x over previous
//
#include <hip/hip_runtime.h>
#include <hip/hip_bf16.h>

// EdgeGNN layer: linear1(relu) -> SpMM (CSR counting-sort + gather) -> linear2(relu) -> GRUCell
// E=200000, NNZ=1600000, EF=16, M=128. bf16 MFMA for GEMMs; no f32 atomics.
// R18: launch-graph parallelism. linear1 and hist are DAG-independent but the
//      single stream serialized them (~63us). Fused into one dispatch by
//      block-range: blocks [0,3125) = linear1 body, [3125,9375) = hist body.
//      Dispatcher overlap hides hist's atomics under linear1's MFMA/HBM.
//      All other kernels byte-identical to R17 (total 407.9; gate pinned at
//      ~137 across 5 falsified hypotheses -- structural floor).

typedef __attribute__((ext_vector_type(4))) float f32x4;
typedef __attribute__((ext_vector_type(8))) short s16x8;

#define MDIM 128
#define EFDIM 16
#define K1PAD 160   // 144 padded to 5*32
#define SCAN_BLK 1024

__device__ __forceinline__ ushort f2bf(float f) {
  union { float f; unsigned u; } v; v.f = f;
  unsigned u = v.u;
  unsigned r = (u + 0x7fffu + ((u >> 16) & 1u)) >> 16;  // RNE
  return (ushort)r;
}
__device__ __forceinline__ float bf2f(ushort h) {
  union { unsigned u; float f; } v; v.u = ((unsigned)h) << 16; return v.f;
}
// native conversion (compiler emits v_cvt_pk_bf16_f32 pairs)
__device__ __forceinline__ short f2bfn(float f) {
  __hip_bfloat16 h = __float2bfloat16(f);
  return *reinterpret_cast<short*>(&h);
}
__device__ __forceinline__ s16x8 cvt8n(f32x4 a, f32x4 b) {
  s16x8 o;
  o[0] = f2bfn(a[0]); o[1] = f2bfn(a[1]); o[2] = f2bfn(a[2]); o[3] = f2bfn(a[3]);
  o[4] = f2bfn(b[0]); o[5] = f2bfn(b[1]); o[6] = f2bfn(b[2]); o[7] = f2bfn(b[3]);
  return o;
}
__device__ __forceinline__ f32x4 mfma16(s16x8 a, s16x8 b, f32x4 c) {
  return __builtin_amdgcn_mfma_f32_16x16x32_bf16(a, b, c, 0, 0, 0);
}
__device__ __forceinline__ float sigmoidf_(float x) { return 1.f / (1.f + __expf(-x)); }
__device__ __forceinline__ float tanhf_(float x) {
  float xc = fminf(fmaxf(x, -15.f), 15.f);
  float t = __expf(2.f * xc);
  return (t - 1.f) / (t + 1.f);
}

// ---------------- prep: bf16 weight conversion ----------------
__global__ __launch_bounds__(256) void prep_kernel(
    const float* __restrict__ W1, const float* __restrict__ W2,
    const float* __restrict__ Wih, const float* __restrict__ Whh,
    ushort* __restrict__ W1b, ushort* __restrict__ W2b,
    ushort* __restrict__ Wihb, ushort* __restrict__ Whhb) {
  int idx = blockIdx.x * 256 + threadIdx.x;
  if (idx < 128 * K1PAD) {
    int n = idx / K1PAD, k = idx % K1PAD;
    W1b[idx] = (k < 144) ? f2bf(W1[n * 144 + k]) : (ushort)0;
    return;
  }
  int i2 = idx - 128 * K1PAD;
  if (i2 < 128 * 128) { W2b[i2] = f2bf(W2[i2]); return; }
  int i3 = i2 - 128 * 128;
  if (i3 < 384 * 128) { Wihb[i3] = f2bf(Wih[i3]); return; }
  int i4 = i3 - 384 * 128;
  if (i4 < 384 * 128) { Whhb[i4] = f2bf(Whh[i4]); return; }
}

// ---------------- fused: linear1 (blocks < nlin1) + hist (blocks >= nlin1) ----------------
// linear1 body = R8/R17 version verbatim; hist body = 1 read + 1 atomic per thread.
__global__ __launch_bounds__(256) void lin1_hist_kernel(
    const float* __restrict__ mo, const float* __restrict__ ef,
    const ushort* __restrict__ W1b, const float* __restrict__ b1,
    ushort* __restrict__ msg1b,
    const int* __restrict__ rows, int* __restrict__ cnt, int nnz, int nlin1) {
  __shared__ ushort w1l[5 * 4096];  // 40KB (hist blocks carry it unused)
  const int tid = threadIdx.x;

  if (blockIdx.x >= nlin1) {
    const int i = (blockIdx.x - nlin1) * 256 + tid;
    if (i < nnz) atomicAdd(&cnt[rows[i]], 1);
    return;
  }

  const int wave = tid >> 6, lane = tid & 63;
  const int r = lane & 15, kg = lane >> 4;
  const int row0 = blockIdx.x * 64 + wave * 16;
  const int arow = row0 + r;

  // stage: 2560 granules, 10/thread. gid = step*512 + col*4 + kg
#pragma unroll
  for (int l = 0; l < 10; ++l) {
    const int gid = l * 256 + tid;
    const int stp = gid >> 9, col = (gid >> 2) & 127, kgs = gid & 3;
    uint4 v = *(const uint4*)(W1b + col * K1PAD + stp * 32 + kgs * 8);
    *(uint4*)&w1l[gid * 8] = v;
  }
  __syncthreads();

  f32x4 acc[8] = {};
#pragma unroll
  for (int step = 0; step < 5; ++step) {
    const int k0 = step * 32 + kg * 8;
    s16x8 a;
    if (k0 < 128) {
      f32x4 f1 = *(const f32x4*)(mo + (size_t)arow * MDIM + k0);
      f32x4 f2 = *(const f32x4*)(mo + (size_t)arow * MDIM + k0 + 4);
      a = cvt8n(f1, f2);
    } else if (k0 < 144) {
      f32x4 f1 = *(const f32x4*)(ef + (size_t)arow * EFDIM + (k0 - 128));
      f32x4 f2 = *(const f32x4*)(ef + (size_t)arow * EFDIM + (k0 - 128) + 4);
      a = cvt8n(f1, f2);
    } else {
      a = (s16x8){0, 0, 0, 0, 0, 0, 0, 0};
    }
#pragma unroll
    for (int f = 0; f < 8; ++f) {
      s16x8 b = *(const s16x8*)&w1l[step * 4096 + (f * 16 + r) * 32 + kg * 8];
      acc[f] = mfma16(a, b, acc[f]);
    }
  }
#pragma unroll
  for (int f = 0; f < 8; ++f) {
    const int col = f * 16 + r;
    const float bias = b1[col];
#pragma unroll
    for (int j = 0; j < 4; ++j) {
      const int orow = row0 + kg * 4 + j;
      float v = acc[f][j] + bias;
      v = v > 0.f ? v : 0.f;
      msg1b[(size_t)orow * MDIM + col] = f2bf(v);
    }
  }
}

// ---------------- CSR build: scan -> scatter ----------------
__global__ __launch_bounds__(256) void scan1_kernel(const int* __restrict__ cnt,
                                                    int* __restrict__ excl,
                                                    int* __restrict__ bsums, int n) {
  __shared__ int wsum[4];
  const int t = threadIdx.x;
  const int base = blockIdx.x * SCAN_BLK + t * 4;
  int v[4];
#pragma unroll
  for (int j = 0; j < 4; ++j) v[j] = (base + j < n) ? cnt[base + j] : 0;
  const int s = v[0] + v[1] + v[2] + v[3];
  const int lane = t & 63, wave = t >> 6;
  int inc = s;
#pragma unroll
  for (int d = 1; d < 64; d <<= 1) {
    int o = __shfl_up(inc, d, 64);
    if (lane >= d) inc += o;
  }
  if (lane == 63) wsum[wave] = inc;
  __syncthreads();
  int woff = 0;
#pragma unroll
  for (int wv = 0; wv < 4; ++wv) if (wv < wave) woff += wsum[wv];
  int run = woff + inc - s;
#pragma unroll
  for (int j = 0; j < 4; ++j) {
    if (base + j < n) excl[base + j] = run;
    run += v[j];
  }
  if (t == 0) bsums[blockIdx.x] = wsum[0] + wsum[1] + wsum[2] + wsum[3];
}

__global__ __launch_bounds__(256) void scan2_kernel(int* __restrict__ bsums, int nb) {
  __shared__ int ws[4];
  const int t = threadIdx.x;
  const int v = (t < nb) ? bsums[t] : 0;
  const int lane = t & 63, wave = t >> 6;
  int inc = v;
#pragma unroll
  for (int d = 1; d < 64; d <<= 1) {
    int o = __shfl_up(inc, d, 64);
    if (lane >= d) inc += o;
  }
  if (lane == 63) ws[wave] = inc;
  __syncthreads();
  int woff = 0;
#pragma unroll
  for (int wv = 0; wv < 4; ++wv) if (wv < wave) woff += ws[wv];
  if (t < nb) bsums[t] = woff + inc - v;
}

// scatter computes row base on the fly: base = excl[r] + bsums[r>>10]
__global__ __launch_bounds__(256) void scatter_kernel(
    const int* __restrict__ rows, const int* __restrict__ cols,
    const float* __restrict__ vals, const int* __restrict__ excl,
    const int* __restrict__ bsums, int* __restrict__ row_fill,
    int2* __restrict__ csr, int nnz) {
  int i = blockIdx.x * 256 + threadIdx.x;
  if (i >= nnz) return;
  int r = rows[i];
  int base = excl[r] + bsums[r >> 10];
  int idx = base + atomicAdd(&row_fill[r], 1);
  int2 cv;
  cv.x = cols[i];
  cv.y = __float_as_int(vals[i]);
  csr[idx] = cv;
}

// ---------------- gather SpMM: one wave per row, 4 nnz streams x 16 lanes (R11 version) ----------------
__global__ __launch_bounds__(256) void gather_kernel(
    const int* __restrict__ excl, const int* __restrict__ bsums,
    const int2* __restrict__ csr,
    const ushort* __restrict__ msg1b, ushort* __restrict__ msg2b,
    int E, int nnz) {
  const int w = (blockIdx.x * 256 + threadIdx.x) >> 6;
  if (w >= E) return;
  const int lane = threadIdx.x & 63;
  const int sub = lane >> 4, c = lane & 15;
  const int start = excl[w] + bsums[w >> 10];
  const int end = (w + 1 < E) ? (excl[w + 1] + bsums[(w + 1) >> 10]) : nnz;

  float acc[8] = {};
  int j = start + sub;
  if (j < end) {
    int2 cv = csr[j];
    while (true) {
      const int jn = j + 4;
      const bool more = jn < end;
      int2 cvn = cv;
      if (more) cvn = csr[jn];
      const float val = __int_as_float(cv.y);
      const s16x8 m = *(const s16x8*)(msg1b + (size_t)cv.x * MDIM + c * 8);
#pragma unroll
      for (int t = 0; t < 8; ++t) acc[t] += bf2f((ushort)m[t]) * val;
      if (!more) break;
      cv = cvn;
      j = jn;
    }
  }
#pragma unroll
  for (int t = 0; t < 8; ++t) {
    acc[t] += __shfl_xor(acc[t], 16, 64);
    acc[t] += __shfl_xor(acc[t], 32, 64);
  }
  if (sub == 0) {
    s16x8 o;
#pragma unroll
    for (int t = 0; t < 8; ++t) o[t] = (short)f2bf(acc[t]);
    *(s16x8*)(msg2b + (size_t)w * MDIM + c * 8) = o;
  }
}

// ---------------- msg3 = relu(msg2 @ W2^T + b2), bf16 out (R8 version) ----------------
__global__ __launch_bounds__(256) void msg3_kernel(
    const ushort* __restrict__ msg2b, const ushort* __restrict__ W2b,
    const float* __restrict__ b2, ushort* __restrict__ msg3b) {
  __shared__ ushort w2l[4 * 4096];  // 32KB
  const int tid = threadIdx.x;
  const int wave = tid >> 6, lane = tid & 63;
  const int r = lane & 15, kg = lane >> 4;
  const int row0 = blockIdx.x * 64 + wave * 16;

  // stage: 2048 granules, 8/thread. gid = step*512 + col*4 + kg
#pragma unroll
  for (int l = 0; l < 8; ++l) {
    const int gid = l * 256 + tid;
    const int stp = gid >> 9, col = (gid >> 2) & 127, kgs = gid & 3;
    uint4 v = *(const uint4*)(W2b + col * MDIM + stp * 32 + kgs * 8);
    *(uint4*)&w2l[gid * 8] = v;
  }

  s16x8 a1[4];
#pragma unroll
  for (int step = 0; step < 4; ++step)
    a1[step] = *(const s16x8*)(msg2b + (size_t)(row0 + r) * MDIM + step * 32 + kg * 8);
  __syncthreads();

  f32x4 acc[8] = {};
#pragma unroll
  for (int step = 0; step < 4; ++step) {
#pragma unroll
    for (int f = 0; f < 8; ++f) {
      s16x8 b = *(const s16x8*)&w2l[step * 4096 + (f * 16 + r) * 32 + kg * 8];
      acc[f] = mfma16(a1[step], b, acc[f]);
    }
  }
#pragma unroll
  for (int f = 0; f < 8; ++f) {
    const int col = f * 16 + r;
    const float bias = b2[col];
#pragma unroll
    for (int j = 0; j < 4; ++j) {
      const int orow = row0 + kg * 4 + j;
      float v = acc[f][j] + bias;
      v = v > 0.f ? v : 0.f;
      msg3b[(size_t)orow * MDIM + col] = f2bf(v);
    }
  }
}

// ---------------- gate_kernel: GRU gates, 4-way column split (R17 version) ----------------
// XCD-aware bijective swizzle (m204): the 4 cg-blocks of a row-tile get
// contiguous wgids -> same XCD -> A-panels (msg3, mo) hit that XCD's L2.
__global__ __launch_bounds__(512, 4) void gate_kernel(
    const ushort* __restrict__ msg3b, const float* __restrict__ mo,
    const ushort* __restrict__ Wihb, const ushort* __restrict__ Whhb,
    const float* __restrict__ bih, const float* __restrict__ bhh,
    float* __restrict__ out, int E) {
  __shared__ ushort wl[6 * 4096];  // 48KB: sec l = [l*4096, +4096), 32 rows x 128
  const int tid = threadIdx.x;

  const int nwg = gridDim.x;
  const int orig = blockIdx.x;
  const int q = nwg >> 3, rm = nwg & 7;
  const int xcd = orig & 7, bidx = orig >> 3;
  const int wgid = (xcd < rm ? xcd * (q + 1) : rm * (q + 1) + (xcd - rm) * q) + bidx;
  const int cg = wgid & 3;
  const int row0 = (wgid >> 2) * 128;

  const int wave = tid >> 6, lane = tid & 63;
  const int r = lane & 15, kg = lane >> 4;

  // stage weights: sec l, local row lr (0..31), granule g (0..15)
  const int lr = tid >> 4, g = tid & 15;
#pragma unroll
  for (int l = 0; l < 6; ++l) {
    const ushort* src = (l & 1) ? Whhb : Wihb;
    const int gate = l >> 1;
    uint4 v = *(const uint4*)(src + (size_t)(gate * 128 + cg * 32 + lr) * MDIM + g * 8);
    *(uint4*)&wl[l * 4096 + lr * 128 + ((g * 8) ^ ((lr & 7) << 3))] = v;
  }

  // A-fragments (row-clamped)
  const int arow0 = row0 + wave * 16 + r;
  const int arow = arow0 < E ? arow0 : E - 1;
  s16x8 ai[4], ah[4];
#pragma unroll
  for (int step = 0; step < 4; ++step) {
    const int k0 = step * 32 + kg * 8;
    ai[step] = *(const s16x8*)(msg3b + (size_t)arow * MDIM + k0);
    f32x4 f1 = *(const f32x4*)(mo + (size_t)arow * MDIM + k0);
    f32x4 f2 = *(const f32x4*)(mo + (size_t)arow * MDIM + k0 + 4);
    ah[step] = cvt8n(f1, f2);
  }
  __syncthreads();

  float outv[8];
#pragma unroll
  for (int p = 0; p < 2; ++p) {
    const int slr = p * 16 + r;           // section-local weight row
    f32x4 a_ir = {}, a_hr = {}, a_iz = {}, a_hz = {}, a_in = {}, a_hn = {};
#pragma unroll
    for (int step = 0; step < 4; ++step) {
      const int k0 = step * 32 + kg * 8;
      const int sw = slr * 128 + (k0 ^ ((slr & 7) << 3));
      s16x8 b_ir = *(const s16x8*)&wl[0 * 4096 + sw];
      s16x8 b_hr = *(const s16x8*)&wl[1 * 4096 + sw];
      a_ir = mfma16(ai[step], b_ir, a_ir);
      a_hr = mfma16(ah[step], b_hr, a_hr);
      s16x8 b_iz = *(const s16x8*)&wl[2 * 4096 + sw];
      s16x8 b_hz = *(const s16x8*)&wl[3 * 4096 + sw];
      a_iz = mfma16(ai[step], b_iz, a_iz);
      a_hz = mfma16(ah[step], b_hz, a_hz);
      s16x8 b_in = *(const s16x8*)&wl[4 * 4096 + sw];
      s16x8 b_hn = *(const s16x8*)&wl[5 * 4096 + sw];
      a_in = mfma16(ai[step], b_in, a_in);
      a_hn = mfma16(ah[step], b_hn, a_hn);
    }
    const int c128 = cg * 32 + p * 16 + r;
    const float bi_r = bih[c128], bh_r = bhh[c128];
    const float bi_z = bih[128 + c128], bh_z = bhh[128 + c128];
    const float bi_n = bih[256 + c128], bh_n = bhh[256 + c128];
#pragma unroll
    for (int j = 0; j < 4; ++j) {
      const int orow0 = row0 + wave * 16 + kg * 4 + j;
      const int orow = orow0 < E ? orow0 : E - 1;
      const float rr_ = sigmoidf_((a_ir[j] + bi_r) + (a_hr[j] + bh_r));
      const float zz = sigmoidf_((a_iz[j] + bi_z) + (a_hz[j] + bh_z));
      const float nn = tanhf_((a_in[j] + bi_n) + rr_ * (a_hn[j] + bh_n));
      const float m = mo[(size_t)orow * MDIM + c128];
      outv[p * 4 + j] = (1.f - zz) * nn + zz * m;
    }
  }

  // store burst; nontemporal (out is never re-read; keep L2 for A panels)
#pragma unroll
  for (int p = 0; p < 2; ++p) {
    const int c128 = cg * 32 + p * 16 + r;
#pragma unroll
    for (int j = 0; j < 4; ++j) {
      const int orow = row0 + wave * 16 + kg * 4 + j;
      if (orow < E)
        __builtin_nontemporal_store(outv[p * 4 + j], out + (size_t)orow * MDIM + c128);
    }
  }
}

extern "C" void kernel_launch(void* const* d_in, const int* in_sizes, int n_in,
                              void* d_out, int out_size, void* d_ws, size_t ws_size,
                              hipStream_t stream) {
  const float* ef   = (const float*)d_in[0];
  const float* mo   = (const float*)d_in[1];
  const int*   arow = (const int*)d_in[2];
  const int*   acol = (const int*)d_in[3];
  const float* aval = (const float*)d_in[4];
  const float* W1   = (const float*)d_in[5];
  const float* b1   = (const float*)d_in[6];
  const float* W2   = (const float*)d_in[7];
  const float* b2   = (const float*)d_in[8];
  const float* Wih  = (const float*)d_in[9];
  const float* Whh  = (const float*)d_in[10];
  const float* bih  = (const float*)d_in[11];
  const float* bhh  = (const float*)d_in[12];
  float* out = (float*)d_out;

  const int E   = in_sizes[0] / EFDIM;   // 200000
  const int nnz = in_sizes[2];           // 1600000

  char* w = (char*)d_ws;
  size_t off = 0;
  ushort* msg1b   = (ushort*)(w + off); off += (size_t)E * MDIM * 2;   // 51.2 MB
  ushort* msg2b   = (ushort*)(w + off); off += (size_t)E * MDIM * 2;   // 51.2 MB
  ushort* msg3b   = (ushort*)(w + off); off += (size_t)E * MDIM * 2;   // 51.2 MB
  int*    row_cnt = (int*)(w + off);    off += (size_t)E * 4;
  int*    row_fill= (int*)(w + off);    off += (size_t)E * 4;          // adjacent to row_cnt
  int*    excl    = (int*)(w + off);    off += (size_t)E * 4;
  int*    bsums   = (int*)(w + off);    off += 256 * 4;
  int2*   csr     = (int2*)(w + off);   off += (size_t)nnz * 8;        // 12.8 MB
  ushort* W1b     = (ushort*)(w + off); off += 128 * K1PAD * 2;
  ushort* W2b     = (ushort*)(w + off); off += 128 * 128 * 2;
  ushort* Wihb    = (ushort*)(w + off); off += 384 * 128 * 2;
  ushort* Whhb    = (ushort*)(w + off); off += 384 * 128 * 2;
  if (off > ws_size) return;  // needs ~170 MB

  const int prep_elems = 128 * K1PAD + 128 * 128 + 2 * 384 * 128;
  prep_kernel<<<(prep_elems + 255) / 256, 256, 0, stream>>>(W1, W2, Wih, Whh,
                                                            W1b, W2b, Wihb, Whhb);

  // memset must precede the fused launch (hist accumulates into row_cnt)
  hipMemsetAsync(row_cnt, 0, (size_t)E * 8, stream);

  // fused linear1 + hist (DAG-independent; overlap in one dispatch)
  {
    const int nlin1 = E / 64;                      // 3125
    const int nhist = (nnz + 255) / 256;           // 6250
    lin1_hist_kernel<<<nlin1 + nhist, 256, 0, stream>>>(mo, ef, W1b, b1, msg1b,
                                                        arow, row_cnt, nnz, nlin1);
  }

  // CSR build: scan -> scatter
  const int nscan = (E + SCAN_BLK - 1) / SCAN_BLK;  // 196 blocks
  scan1_kernel<<<nscan, 256, 0, stream>>>(row_cnt, excl, bsums, E);
  scan2_kernel<<<1, 256, 0, stream>>>(bsums, nscan);
  scatter_kernel<<<(nnz + 255) / 256, 256, 0, stream>>>(arow, acol, aval, excl, bsums,
                                                        row_fill, csr, nnz);

  // gather SpMM
  {
    const long long total = (long long)E * 64;
    const int grid = (int)((total + 255) / 256);
    gather_kernel<<<grid, 256, 0, stream>>>(excl, bsums, csr, msg1b, msg2b, E, nnz);
  }

  // linear2 + GRU gates
  msg3_kernel<<<E / 64, 256, 0, stream>>>(msg2b, W2b, b2, msg3b);
  {
    const int nrt = (E + 127) / 128;  // 1563
    gate_kernel<<<nrt * 4, 512, 0, stream>>>(msg3b, mo, Wihb, Whhb, bih, bhh, out, E);
  }
}